// Round 1
// baseline (1541.902 us; speedup 1.0000x reference)
//
#include <hip/hip_runtime.h>

// Problem constants (DirectedGraphLayer): B=2, N=50000, FIN=128, FOUT=64, E=800000
#define Bc   2
#define Nn   50000
#define FINc 128
#define FOUTc 64
#define Mtot (Bc * Nn)          // 100000 combined (b,n) rows
#define CCOMB 128               // combined output cols: [W | W_self]

// ---------------------------------------------------------------------------
// Kernel 1: dual GEMM.  Computes
//   xr[n*128 + b*64 + o]  = sum_f x[b,n,f] * W[f,o]          (message features)
//   out[(b*N+n)*64 + o]   = sum_f x[b,n,f] * W_self[f,o] + b_self[o]   (pre-ReLU)
// Block: 256 threads. 64 rows per block. Thread tile: 8 rows x 4 cols.
// Col groups 0..15 -> W (cols 0..63), 16..31 -> W_self (cols 0..63).
// ---------------------------------------------------------------------------
__global__ __launch_bounds__(256) void gemm_dual(
    const float* __restrict__ x, const float* __restrict__ W,
    const float* __restrict__ Ws, const float* __restrict__ bself,
    float* __restrict__ xr, float* __restrict__ outp)
{
    const int tid = threadIdx.x;
    const int g   = tid & 31;        // col group 0..31
    const int rg  = tid >> 5;        // row group 0..7
    const int rowbase = blockIdx.x * 64 + rg * 8;

    const float* __restrict__ Wp = (g < 16) ? W : Ws;
    const int c0 = (g & 15) * 4;     // col within the 64-wide matrix

    float acc[8][4];
#pragma unroll
    for (int j = 0; j < 8; ++j)
#pragma unroll
        for (int c = 0; c < 4; ++c) acc[j][c] = 0.0f;

    for (int fc = 0; fc < FINc; fc += 4) {
        // W fragment: W[fc+jf][c0 .. c0+3], jf = 0..3
        float wv[4][4];
#pragma unroll
        for (int jf = 0; jf < 4; ++jf) {
            const float4 w4 = *(const float4*)&Wp[(fc + jf) * FOUTc + c0];
            wv[jf][0] = w4.x; wv[jf][1] = w4.y; wv[jf][2] = w4.z; wv[jf][3] = w4.w;
        }
#pragma unroll
        for (int j = 0; j < 8; ++j) {
            const int r = rowbase + j;
            const int rr = (r < Mtot) ? r : (Mtot - 1);   // clamp (stores guarded later)
            const float4 x4 = *(const float4*)&x[(size_t)rr * FINc + fc];
            const float xs[4] = {x4.x, x4.y, x4.z, x4.w};
#pragma unroll
            for (int c = 0; c < 4; ++c) {
                acc[j][c] = fmaf(xs[0], wv[0][c], acc[j][c]);
                acc[j][c] = fmaf(xs[1], wv[1][c], acc[j][c]);
                acc[j][c] = fmaf(xs[2], wv[2][c], acc[j][c]);
                acc[j][c] = fmaf(xs[3], wv[3][c], acc[j][c]);
            }
        }
    }

    if (g < 16) {
        // message features -> xr in (N, B*FOUT) layout
#pragma unroll
        for (int j = 0; j < 8; ++j) {
            const int r = rowbase + j;
            if (r >= Mtot) break;
            const int b = (r >= Nn) ? 1 : 0;
            const int n = r - b * Nn;
            float4 v = make_float4(acc[j][0], acc[j][1], acc[j][2], acc[j][3]);
            *(float4*)&xr[(size_t)n * CCOMB + b * FOUTc + c0] = v;
        }
    } else {
        const float4 bs = *(const float4*)&bself[c0];
#pragma unroll
        for (int j = 0; j < 8; ++j) {
            const int r = rowbase + j;
            if (r >= Mtot) break;
            float4 v = make_float4(acc[j][0] + bs.x, acc[j][1] + bs.y,
                                   acc[j][2] + bs.z, acc[j][3] + bs.w);
            *(float4*)&outp[(size_t)r * FOUTc + c0] = v;
        }
    }
}

// ---------------------------------------------------------------------------
// Kernel 2: edge gather + scatter-add.  32 threads per edge; each thread
// handles 4 consecutive of the 128 combined feature columns.
// agg[row*128 + f] += val * xr[col*128 + f]
// ---------------------------------------------------------------------------
__global__ __launch_bounds__(256) void edge_scatter(
    const int* __restrict__ erow, const int* __restrict__ ecol,
    const float* __restrict__ eval, const float* __restrict__ xr,
    float* __restrict__ agg, int E)
{
    const long long t = (long long)blockIdx.x * 256 + threadIdx.x;
    const int e = (int)(t >> 5);
    if (e >= E) return;
    const int f0 = ((int)t & 31) * 4;

    const int c = ecol[e];
    const int r = erow[e];
    const float v = eval[e];

    const float4 xv = *(const float4*)&xr[(size_t)c * CCOMB + f0];
    float* ap = &agg[(size_t)r * CCOMB + f0];
    atomicAdd(ap + 0, v * xv.x);
    atomicAdd(ap + 1, v * xv.y);
    atomicAdd(ap + 2, v * xv.z);
    atomicAdd(ap + 3, v * xv.w);
}

// ---------------------------------------------------------------------------
// Kernel 3: finalize.  out[b,n,o] = relu(self_pre[b,n,o] + agg[n,b*64+o])
// One float4 per thread.
// ---------------------------------------------------------------------------
__global__ __launch_bounds__(256) void finalize(
    const float* __restrict__ agg, float* __restrict__ outp)
{
    const int t = blockIdx.x * 256 + threadIdx.x;
    const long long idx4 = (long long)t * 4;
    if (idx4 >= (long long)Mtot * FOUTc) return;
    const int r = (int)(idx4 >> 6);   // combined row m = b*N + n
    const int o = (int)(idx4 & 63);
    const int b = (r >= Nn) ? 1 : 0;
    const int n = r - b * Nn;

    const float4 a = *(const float4*)&agg[(size_t)n * CCOMB + b * FOUTc + o];
    float4 s = *(float4*)&outp[idx4];
    s.x = fmaxf(s.x + a.x, 0.0f);
    s.y = fmaxf(s.y + a.y, 0.0f);
    s.z = fmaxf(s.z + a.z, 0.0f);
    s.w = fmaxf(s.w + a.w, 0.0f);
    *(float4*)&outp[idx4] = s;
}

extern "C" void kernel_launch(void* const* d_in, const int* in_sizes, int n_in,
                              void* d_out, int out_size, void* d_ws, size_t ws_size,
                              hipStream_t stream)
{
    const float* x    = (const float*)d_in[0];
    const float* W    = (const float*)d_in[1];
    const float* Ws   = (const float*)d_in[2];
    const float* bs   = (const float*)d_in[3];
    const int*   erow = (const int*)d_in[4];
    const int*   ecol = (const int*)d_in[5];
    const float* eval = (const float*)d_in[6];
    float* outp = (float*)d_out;

    float* xr  = (float*)d_ws;                       // N*128 floats = 25.6 MB
    float* agg = xr + (size_t)Nn * CCOMB;            // N*128 floats = 25.6 MB
    const int E = in_sizes[4];

    // agg must be zero every call (ws is re-poisoned to 0xAA by the harness)
    hipMemsetAsync(agg, 0, (size_t)Nn * CCOMB * sizeof(float), stream);

    // dense: xr and pre-ReLU self term
    gemm_dual<<<(Mtot + 63) / 64, 256, 0, stream>>>(x, W, Ws, bs, xr, outp);

    // sparse: gather/scale/scatter-add
    const long long ethreads = (long long)E * 32;
    edge_scatter<<<(int)((ethreads + 255) / 256), 256, 0, stream>>>(
        erow, ecol, eval, xr, agg, E);

    // combine + ReLU
    finalize<<<((Mtot * FOUTc / 4) + 255) / 256, 256, 0, stream>>>(agg, outp);
}

// Round 2
// 343.642 us; speedup vs baseline: 4.4869x; 4.4869x over previous
//
#include <hip/hip_runtime.h>

// Problem constants (DirectedGraphLayer): B=2, N=50000, FIN=128, FOUT=64, E=800000
#define Bc   2
#define Nn   50000
#define FINc 128
#define FOUTc 64
#define Mtot (Bc * Nn)          // 100000 combined (b,n) rows
#define CCOMB 128               // combined feature cols in xr: [b0 o0..63 | b1 o0..63]

// ---------------------------------------------------------------------------
// Kernel 1: dual GEMM (unchanged from R1).
//   xr[n*128 + b*64 + o]  = sum_f x[b,n,f] * W[f,o]
//   out[(b*N+n)*64 + o]   = sum_f x[b,n,f] * W_self[f,o] + b_self[o]  (pre-ReLU)
// ---------------------------------------------------------------------------
__global__ __launch_bounds__(256) void gemm_dual(
    const float* __restrict__ x, const float* __restrict__ W,
    const float* __restrict__ Ws, const float* __restrict__ bself,
    float* __restrict__ xr, float* __restrict__ outp)
{
    const int tid = threadIdx.x;
    const int g   = tid & 31;        // col group 0..31
    const int rg  = tid >> 5;        // row group 0..7
    const int rowbase = blockIdx.x * 64 + rg * 8;

    const float* __restrict__ Wp = (g < 16) ? W : Ws;
    const int c0 = (g & 15) * 4;

    float acc[8][4];
#pragma unroll
    for (int j = 0; j < 8; ++j)
#pragma unroll
        for (int c = 0; c < 4; ++c) acc[j][c] = 0.0f;

    for (int fc = 0; fc < FINc; fc += 4) {
        float wv[4][4];
#pragma unroll
        for (int jf = 0; jf < 4; ++jf) {
            const float4 w4 = *(const float4*)&Wp[(fc + jf) * FOUTc + c0];
            wv[jf][0] = w4.x; wv[jf][1] = w4.y; wv[jf][2] = w4.z; wv[jf][3] = w4.w;
        }
#pragma unroll
        for (int j = 0; j < 8; ++j) {
            const int r = rowbase + j;
            const int rr = (r < Mtot) ? r : (Mtot - 1);
            const float4 x4 = *(const float4*)&x[(size_t)rr * FINc + fc];
            const float xs[4] = {x4.x, x4.y, x4.z, x4.w};
#pragma unroll
            for (int c = 0; c < 4; ++c) {
                acc[j][c] = fmaf(xs[0], wv[0][c], acc[j][c]);
                acc[j][c] = fmaf(xs[1], wv[1][c], acc[j][c]);
                acc[j][c] = fmaf(xs[2], wv[2][c], acc[j][c]);
                acc[j][c] = fmaf(xs[3], wv[3][c], acc[j][c]);
            }
        }
    }

    if (g < 16) {
#pragma unroll
        for (int j = 0; j < 8; ++j) {
            const int r = rowbase + j;
            if (r >= Mtot) break;
            const int b = (r >= Nn) ? 1 : 0;
            const int n = r - b * Nn;
            float4 v = make_float4(acc[j][0], acc[j][1], acc[j][2], acc[j][3]);
            *(float4*)&xr[(size_t)n * CCOMB + b * FOUTc + c0] = v;
        }
    } else {
        const float4 bs = *(const float4*)&bself[c0];
#pragma unroll
        for (int j = 0; j < 8; ++j) {
            const int r = rowbase + j;
            if (r >= Mtot) break;
            float4 v = make_float4(acc[j][0] + bs.x, acc[j][1] + bs.y,
                                   acc[j][2] + bs.z, acc[j][3] + bs.w);
            *(float4*)&outp[(size_t)r * FOUTc + c0] = v;
        }
    }
}

// ---------------------------------------------------------------------------
// Edge bucketing pipeline: counts -> exclusive scan -> scatter (col,val) into
// per-row segments. Replaces 102.4M feature atomics with 1.6M index atomics.
// ---------------------------------------------------------------------------
__global__ __launch_bounds__(256) void count_rows(
    const int* __restrict__ erow, int* __restrict__ cnt, int E)
{
    const int e = blockIdx.x * 256 + threadIdx.x;
    if (e >= E) return;
    atomicAdd(&cnt[erow[e]], 1);
}

__global__ __launch_bounds__(256) void block_sum(
    const int* __restrict__ cnt, int* __restrict__ bsum)
{
    __shared__ int s[256];
    const int t = threadIdx.x;
    const int idx = blockIdx.x * 256 + t;
    s[t] = (idx < Nn) ? cnt[idx] : 0;
    __syncthreads();
    for (int off = 128; off > 0; off >>= 1) {
        if (t < off) s[t] += s[t + off];
        __syncthreads();
    }
    if (t == 0) bsum[blockIdx.x] = s[0];
}

__global__ __launch_bounds__(256) void scan_bsum(
    const int* __restrict__ bsum, int* __restrict__ bscan, int nb)
{
    __shared__ int s[256];
    const int t = threadIdx.x;
    const int v = (t < nb) ? bsum[t] : 0;
    s[t] = v;
    __syncthreads();
    for (int off = 1; off < 256; off <<= 1) {
        const int add = (t >= off) ? s[t - off] : 0;
        __syncthreads();
        s[t] += add;
        __syncthreads();
    }
    if (t < nb) bscan[t] = s[t] - v;   // exclusive
}

__global__ __launch_bounds__(256) void fill_starts(
    const int* __restrict__ cnt, const int* __restrict__ bscan,
    int* __restrict__ rowstart, int* __restrict__ cursor, int E)
{
    __shared__ int s[256];
    const int t = threadIdx.x;
    const int idx = blockIdx.x * 256 + t;
    const int v = (idx < Nn) ? cnt[idx] : 0;
    s[t] = v;
    __syncthreads();
    for (int off = 1; off < 256; off <<= 1) {
        const int add = (t >= off) ? s[t - off] : 0;
        __syncthreads();
        s[t] += add;
        __syncthreads();
    }
    const int start = bscan[blockIdx.x] + (s[t] - v);
    if (idx < Nn) { rowstart[idx] = start; cursor[idx] = start; }
    if (idx == 0) rowstart[Nn] = E;
}

__global__ __launch_bounds__(256) void bucket(
    const int* __restrict__ erow, const int* __restrict__ ecol,
    const float* __restrict__ evalv, int* __restrict__ cursor,
    int* __restrict__ cs, float* __restrict__ vs, int E)
{
    const int e = blockIdx.x * 256 + threadIdx.x;
    if (e >= E) return;
    const int r = erow[e];
    const int pos = atomicAdd(&cursor[r], 1);
    cs[pos] = ecol[e];
    vs[pos] = evalv[e];
}

// ---------------------------------------------------------------------------
// Kernel: per-row gather-reduce, fused with finalize.
// One wave (64 lanes) per row; lane L owns combined cols 2L, 2L+1.
// acc = sum_{e in row} val[e] * xr[col[e]][:]; out = relu(self_pre + acc)
// ---------------------------------------------------------------------------
__global__ __launch_bounds__(256) void row_gather(
    const int* __restrict__ rowstart, const int* __restrict__ cs,
    const float* __restrict__ vs, const float* __restrict__ xr,
    float* __restrict__ outp)
{
    const int lane = threadIdx.x & 63;
    int n = blockIdx.x * 4 + (threadIdx.x >> 6);
    n = __builtin_amdgcn_readfirstlane(n);   // wave-uniform -> scalar loads

    const int s    = rowstart[n];
    const int eend = rowstart[n + 1];
    const int c0   = lane * 2;

    float a0 = 0.0f, a1 = 0.0f;
    for (int e = s; e < eend; ++e) {
        const int   c = cs[e];
        const float v = vs[e];
        const float2 xv = *(const float2*)&xr[(size_t)c * CCOMB + c0];
        a0 = fmaf(v, xv.x, a0);
        a1 = fmaf(v, xv.y, a1);
    }

    const int b = lane >> 5;
    const int o = (lane & 31) * 2;
    const size_t oidx = ((size_t)b * Nn + n) * FOUTc + o;
    const float2 sp = *(const float2*)&outp[oidx];
    float2 r;
    r.x = fmaxf(sp.x + a0, 0.0f);
    r.y = fmaxf(sp.y + a1, 0.0f);
    *(float2*)&outp[oidx] = r;
}

extern "C" void kernel_launch(void* const* d_in, const int* in_sizes, int n_in,
                              void* d_out, int out_size, void* d_ws, size_t ws_size,
                              hipStream_t stream)
{
    const float* x    = (const float*)d_in[0];
    const float* W    = (const float*)d_in[1];
    const float* Ws   = (const float*)d_in[2];
    const float* bs   = (const float*)d_in[3];
    const int*   erow = (const int*)d_in[4];
    const int*   ecol = (const int*)d_in[5];
    const float* eval = (const float*)d_in[6];
    float* outp = (float*)d_out;
    const int E = in_sizes[4];

    // workspace layout
    float* xr       = (float*)d_ws;                    // N*128 floats = 25.6 MB
    int*   rowstart = (int*)(xr + (size_t)Nn * CCOMB); // N+1
    int*   cursor   = rowstart + (Nn + 1);             // N  (doubles as counts)
    int*   cs       = cursor + Nn;                     // E
    float* vs       = (float*)(cs + E);                // E
    int*   bsum     = (int*)(vs + E);                  // ceil(N/256)
    int*   bscan    = bsum + 256;                      // ceil(N/256)

    const int NB = (Nn + 255) / 256;                   // 196 blocks over rows
    const int EB = (E + 255) / 256;                    // blocks over edges

    // 1. dense part (independent of edge pipeline)
    gemm_dual<<<(Mtot + 63) / 64, 256, 0, stream>>>(x, W, Ws, bs, xr, outp);

    // 2. edge bucketing: counts -> scan -> segments
    hipMemsetAsync(cursor, 0, (size_t)Nn * sizeof(int), stream);
    count_rows<<<EB, 256, 0, stream>>>(erow, cursor, E);
    block_sum<<<NB, 256, 0, stream>>>(cursor, bsum);
    scan_bsum<<<1, 256, 0, stream>>>(bsum, bscan, NB);
    fill_starts<<<NB, 256, 0, stream>>>(cursor, bscan, rowstart, cursor, E);
    bucket<<<EB, 256, 0, stream>>>(erow, ecol, eval, cursor, cs, vs, E);

    // 3. per-row gather-reduce fused with self+bias+ReLU finalize
    row_gather<<<Nn / 4, 256, 0, stream>>>(rowstart, cs, vs, xr, outp);
}

// Round 3
// 301.464 us; speedup vs baseline: 5.1147x; 1.1399x over previous
//
#include <hip/hip_runtime.h>

// Problem constants (DirectedGraphLayer): B=2, N=50000, FIN=128, FOUT=64, E=800000
#define Bc   2
#define Nn   50000
#define FINc 128
#define FOUTc 64
#define Mtot (Bc * Nn)          // 100000 combined (b,n) rows
#define CCOMB 128               // combined feature cols in xr: [b0 o0..63 | b1 o0..63]

// ---------------------------------------------------------------------------
// Kernel 1: dual GEMM with LDS-staged x tile.
//   xr[n*128 + b*64 + o]  = sum_f x[b,n,f] * W[f,o]
//   out[(b*N+n)*64 + o]   = sum_f x[b,n,f] * W_self[f,o] + b_self[o]  (pre-ReLU)
// Block: 256 threads, 64 rows. x tile (64x128 f32 = 32 KB) staged in LDS once;
// inner loop reads LDS (2 distinct addrs/wave -> broadcast + free 2-way).
// ---------------------------------------------------------------------------
__global__ __launch_bounds__(256) void gemm_dual(
    const float* __restrict__ x, const float* __restrict__ W,
    const float* __restrict__ Ws, const float* __restrict__ bself,
    float* __restrict__ xr, float* __restrict__ outp)
{
    __shared__ float xs[64][FINc];   // 32 KB

    const int tid = threadIdx.x;
    const int rowbase = blockIdx.x * 64;

    // cooperative tile load: 64 rows x 32 float4 = 2048 float4, 8 per thread
#pragma unroll
    for (int i = 0; i < 8; ++i) {
        const int idx4 = i * 256 + tid;
        const int r = idx4 >> 5;              // 32 float4 per row
        const int c = (idx4 & 31) * 4;
        const int gr = rowbase + r;
        float4 v = (gr < Mtot) ? *(const float4*)&x[(size_t)gr * FINc + c]
                               : make_float4(0.f, 0.f, 0.f, 0.f);
        *(float4*)&xs[r][c] = v;
    }
    __syncthreads();

    const int g  = tid & 31;         // col group 0..31
    const int rg = tid >> 5;         // row group 0..7
    const float* __restrict__ Wp = (g < 16) ? W : Ws;
    const int c0 = (g & 15) * 4;

    float acc[8][4];
#pragma unroll
    for (int j = 0; j < 8; ++j)
#pragma unroll
        for (int c = 0; c < 4; ++c) acc[j][c] = 0.0f;

    for (int fc = 0; fc < FINc; fc += 4) {
        float wv[4][4];
#pragma unroll
        for (int jf = 0; jf < 4; ++jf) {
            const float4 w4 = *(const float4*)&Wp[(fc + jf) * FOUTc + c0];
            wv[jf][0] = w4.x; wv[jf][1] = w4.y; wv[jf][2] = w4.z; wv[jf][3] = w4.w;
        }
#pragma unroll
        for (int j = 0; j < 8; ++j) {
            const float4 x4 = *(const float4*)&xs[rg * 8 + j][fc];
            const float xsv[4] = {x4.x, x4.y, x4.z, x4.w};
#pragma unroll
            for (int c = 0; c < 4; ++c) {
                acc[j][c] = fmaf(xsv[0], wv[0][c], acc[j][c]);
                acc[j][c] = fmaf(xsv[1], wv[1][c], acc[j][c]);
                acc[j][c] = fmaf(xsv[2], wv[2][c], acc[j][c]);
                acc[j][c] = fmaf(xsv[3], wv[3][c], acc[j][c]);
            }
        }
    }

    if (g < 16) {
#pragma unroll
        for (int j = 0; j < 8; ++j) {
            const int r = rowbase + rg * 8 + j;
            if (r >= Mtot) break;
            const int b = (r >= Nn) ? 1 : 0;
            const int n = r - b * Nn;
            float4 v = make_float4(acc[j][0], acc[j][1], acc[j][2], acc[j][3]);
            *(float4*)&xr[(size_t)n * CCOMB + b * FOUTc + c0] = v;
        }
    } else {
        const float4 bsv = *(const float4*)&bself[c0];
#pragma unroll
        for (int j = 0; j < 8; ++j) {
            const int r = rowbase + rg * 8 + j;
            if (r >= Mtot) break;
            float4 v = make_float4(acc[j][0] + bsv.x, acc[j][1] + bsv.y,
                                   acc[j][2] + bsv.z, acc[j][3] + bsv.w);
            *(float4*)&outp[(size_t)r * FOUTc + c0] = v;
        }
    }
}

// ---------------------------------------------------------------------------
// Edge bucketing: counts -> exclusive scan -> scatter packed (col,val) int2
// into per-row segments.
// ---------------------------------------------------------------------------
__global__ __launch_bounds__(256) void count_rows(
    const int* __restrict__ erow, int* __restrict__ cnt, int E)
{
    const int e = blockIdx.x * 256 + threadIdx.x;
    if (e >= E) return;
    atomicAdd(&cnt[erow[e]], 1);
}

__global__ __launch_bounds__(256) void block_sum(
    const int* __restrict__ cnt, int* __restrict__ bsum)
{
    __shared__ int s[256];
    const int t = threadIdx.x;
    const int idx = blockIdx.x * 256 + t;
    s[t] = (idx < Nn) ? cnt[idx] : 0;
    __syncthreads();
    for (int off = 128; off > 0; off >>= 1) {
        if (t < off) s[t] += s[t + off];
        __syncthreads();
    }
    if (t == 0) bsum[blockIdx.x] = s[0];
}

__global__ __launch_bounds__(256) void scan_bsum(
    const int* __restrict__ bsum, int* __restrict__ bscan, int nb)
{
    __shared__ int s[256];
    const int t = threadIdx.x;
    const int v = (t < nb) ? bsum[t] : 0;
    s[t] = v;
    __syncthreads();
    for (int off = 1; off < 256; off <<= 1) {
        const int add = (t >= off) ? s[t - off] : 0;
        __syncthreads();
        s[t] += add;
        __syncthreads();
    }
    if (t < nb) bscan[t] = s[t] - v;   // exclusive
}

__global__ __launch_bounds__(256) void fill_starts(
    const int* __restrict__ cnt, const int* __restrict__ bscan,
    int* __restrict__ rowstart, int* __restrict__ cursor, int E)
{
    __shared__ int s[256];
    const int t = threadIdx.x;
    const int idx = blockIdx.x * 256 + t;
    const int v = (idx < Nn) ? cnt[idx] : 0;
    s[t] = v;
    __syncthreads();
    for (int off = 1; off < 256; off <<= 1) {
        const int add = (t >= off) ? s[t - off] : 0;
        __syncthreads();
        s[t] += add;
        __syncthreads();
    }
    const int start = bscan[blockIdx.x] + (s[t] - v);
    if (idx < Nn) { rowstart[idx] = start; cursor[idx] = start; }
    if (idx == 0) rowstart[Nn] = E;
}

__global__ __launch_bounds__(256) void bucket(
    const int* __restrict__ erow, const int* __restrict__ ecol,
    const float* __restrict__ evalv, int* __restrict__ cursor,
    int2* __restrict__ cv, int E)
{
    const int e = blockIdx.x * 256 + threadIdx.x;
    if (e >= E) return;
    const int r = erow[e];
    const int pos = atomicAdd(&cursor[r], 1);
    cv[pos] = make_int2(ecol[e], __float_as_int(evalv[e]));
}

// ---------------------------------------------------------------------------
// Per-row gather-reduce fused with finalize. One wave per row; lane L owns
// combined cols 2L,2L+1. 2-edge unroll for memory-level parallelism.
// ---------------------------------------------------------------------------
__global__ __launch_bounds__(256) void row_gather(
    const int* __restrict__ rowstart, const int2* __restrict__ cv,
    const float* __restrict__ xr, float* __restrict__ outp)
{
    const int lane = threadIdx.x & 63;
    int n = blockIdx.x * 4 + (threadIdx.x >> 6);
    n = __builtin_amdgcn_readfirstlane(n);   // wave-uniform -> scalar loads

    const int s    = rowstart[n];
    const int eend = rowstart[n + 1];
    const int c0   = lane * 2;

    float a0 = 0.f, a1 = 0.f, b0 = 0.f, b1 = 0.f;
    int e = s;
    for (; e + 2 <= eend; e += 2) {
        const int2 e0 = cv[e];
        const int2 e1 = cv[e + 1];
        const float2 x0 = *(const float2*)&xr[(size_t)e0.x * CCOMB + c0];
        const float2 x1 = *(const float2*)&xr[(size_t)e1.x * CCOMB + c0];
        const float v0 = __int_as_float(e0.y);
        const float v1 = __int_as_float(e1.y);
        a0 = fmaf(v0, x0.x, a0);
        a1 = fmaf(v0, x0.y, a1);
        b0 = fmaf(v1, x1.x, b0);
        b1 = fmaf(v1, x1.y, b1);
    }
    if (e < eend) {
        const int2 e0 = cv[e];
        const float2 x0 = *(const float2*)&xr[(size_t)e0.x * CCOMB + c0];
        const float v0 = __int_as_float(e0.y);
        a0 = fmaf(v0, x0.x, a0);
        a1 = fmaf(v0, x0.y, a1);
    }
    a0 += b0; a1 += b1;

    const int b = lane >> 5;
    const int o = (lane & 31) * 2;
    const size_t oidx = ((size_t)b * Nn + n) * FOUTc + o;
    const float2 sp = *(const float2*)&outp[oidx];
    float2 r;
    r.x = fmaxf(sp.x + a0, 0.0f);
    r.y = fmaxf(sp.y + a1, 0.0f);
    *(float2*)&outp[oidx] = r;
}

extern "C" void kernel_launch(void* const* d_in, const int* in_sizes, int n_in,
                              void* d_out, int out_size, void* d_ws, size_t ws_size,
                              hipStream_t stream)
{
    const float* x    = (const float*)d_in[0];
    const float* W    = (const float*)d_in[1];
    const float* Ws   = (const float*)d_in[2];
    const float* bs   = (const float*)d_in[3];
    const int*   erow = (const int*)d_in[4];
    const int*   ecol = (const int*)d_in[5];
    const float* eval = (const float*)d_in[6];
    float* outp = (float*)d_out;
    const int E = in_sizes[4];

    // workspace layout (cv 8-byte aligned: xr is 25,600,000 B)
    float* xr       = (float*)d_ws;                    // N*128 floats = 25.6 MB
    int2*  cv       = (int2*)(xr + (size_t)Nn * CCOMB);// E int2 = 6.4 MB
    int*   rowstart = (int*)(cv + E);                  // N+1
    int*   cursor   = rowstart + (Nn + 2);             // N (doubles as counts)
    int*   bsum     = cursor + Nn;                     // ceil(N/256)
    int*   bscan    = bsum + 256;                      // ceil(N/256)

    const int NB = (Nn + 255) / 256;                   // 196 blocks over rows
    const int EB = (E + 255) / 256;                    // blocks over edges

    // 1. dense part (independent of edge pipeline)
    gemm_dual<<<(Mtot + 63) / 64, 256, 0, stream>>>(x, W, Ws, bs, xr, outp);

    // 2. edge bucketing: counts -> scan -> segments
    hipMemsetAsync(cursor, 0, (size_t)Nn * sizeof(int), stream);
    count_rows<<<EB, 256, 0, stream>>>(erow, cursor, E);
    block_sum<<<NB, 256, 0, stream>>>(cursor, bsum);
    scan_bsum<<<1, 256, 0, stream>>>(bsum, bscan, NB);
    fill_starts<<<NB, 256, 0, stream>>>(cursor, bscan, rowstart, cursor, E);
    bucket<<<EB, 256, 0, stream>>>(erow, ecol, eval, cursor, cv, E);

    // 3. per-row gather-reduce fused with self+bias+ReLU finalize
    row_gather<<<Nn / 4, 256, 0, stream>>>(rowstart, cv, xr, outp);
}

// Round 4
// 279.069 us; speedup vs baseline: 5.5252x; 1.0802x over previous
//
#include <hip/hip_runtime.h>

// Problem constants (DirectedGraphLayer): B=2, N=50000, FIN=128, FOUT=64, E=800000
#define Bc   2
#define Nn   50000
#define FINc 128
#define FOUTc 64
#define Mtot (Bc * Nn)          // 100000 combined (b,n) rows
#define CCOMB 128               // combined feature cols: [W cols 0..63 | W_self cols 0..63]

typedef __bf16 bf16x8 __attribute__((ext_vector_type(8)));
typedef float  f32x4  __attribute__((ext_vector_type(4)));

static __device__ inline unsigned short f2bf(float f) {
    unsigned int u = __float_as_uint(f);
    u += 0x7fffu + ((u >> 16) & 1u);       // round-to-nearest-even
    return (unsigned short)(u >> 16);
}

// ---------------------------------------------------------------------------
// pack_w: build Bpack = [W | W_self] in B-fragment-major bf16 layout.
// Bpack[(nt*4+kt)*64 + lane][j]  (8 bf16 = 16 B per lane entry)
//   = Wc[k = kt*32 + (lane>>4)*8 + j][n = nt*16 + (lane&15)]
// 2048 entries total = 32 KB.
// ---------------------------------------------------------------------------
__global__ __launch_bounds__(256) void pack_w(
    const float* __restrict__ W, const float* __restrict__ Ws,
    unsigned short* __restrict__ Bp)
{
    const int idx = blockIdx.x * 256 + threadIdx.x;
    if (idx >= 2048) return;
    const int lane = idx & 63;
    const int kt   = (idx >> 6) & 3;
    const int nt   = idx >> 8;
    const int n    = nt * 16 + (lane & 15);
    const int k0   = kt * 32 + (lane >> 4) * 8;

    unsigned short o8[8];
#pragma unroll
    for (int j = 0; j < 8; ++j) {
        const int f = k0 + j;
        const float v = (n < 64) ? W[f * FOUTc + n] : Ws[f * FOUTc + (n - 64)];
        o8[j] = f2bf(v);
    }
    *(uint4*)&Bp[(size_t)idx * 8] = *(uint4*)o8;
}

// ---------------------------------------------------------------------------
// gemm_mfma: D(100000x128) = X(100000x128) @ [W|Ws], bf16 MFMA, fp32 acc.
// Block 256 = 4 waves; wave handles 16 rows x 128 cols (8 n-tiles), K-loop 4.
// A from global fp32 (read once), converted in-register. B from Bpack (L2).
// Epilogue: cols 0..63 -> xr (msg features, (N, B*64) layout);
//           cols 64..127 -> outp pre-ReLU self term (+ bias).
// ---------------------------------------------------------------------------
__global__ __launch_bounds__(256) void gemm_mfma(
    const float* __restrict__ x, const unsigned short* __restrict__ Bp,
    const float* __restrict__ bself,
    float* __restrict__ xr, float* __restrict__ outp)
{
    const int wave = threadIdx.x >> 6;
    const int lane = threadIdx.x & 63;
    const int quad = lane >> 4;
    const int mbase = blockIdx.x * 64 + wave * 16;

    const int mrow   = mbase + (lane & 15);
    const int mclamp = (mrow < Mtot) ? mrow : (Mtot - 1);
    const float* __restrict__ xrow = &x[(size_t)mclamp * FINc];

    f32x4 acc[8] = {};

#pragma unroll
    for (int kt = 0; kt < 4; ++kt) {
        const int k0 = kt * 32 + quad * 8;
        const float4 xa = *(const float4*)&xrow[k0];
        const float4 xb = *(const float4*)&xrow[k0 + 4];
        bf16x8 af;
        af[0] = (__bf16)xa.x; af[1] = (__bf16)xa.y;
        af[2] = (__bf16)xa.z; af[3] = (__bf16)xa.w;
        af[4] = (__bf16)xb.x; af[5] = (__bf16)xb.y;
        af[6] = (__bf16)xb.z; af[7] = (__bf16)xb.w;

        const bf16x8* __restrict__ bbase =
            (const bf16x8*)&Bp[(size_t)(kt * 64 + lane) * 8];
#pragma unroll
        for (int nt = 0; nt < 8; ++nt) {
            const bf16x8 bfv = bbase[nt * 4 * 64];   // (nt*4+kt)*64+lane entries
            acc[nt] = __builtin_amdgcn_mfma_f32_16x16x32_bf16(af, bfv, acc[nt], 0, 0, 0);
        }
    }

    // epilogue: C/D layout col=lane&15, row=quad*4+reg
    const int col_lo = lane & 15;
#pragma unroll
    for (int nt = 0; nt < 8; ++nt) {
        const int c = nt * 16 + col_lo;
        const float bias = (c >= 64) ? bself[c - 64] : 0.0f;
#pragma unroll
        for (int r = 0; r < 4; ++r) {
            const int m = mbase + quad * 4 + r;
            if (m >= Mtot) continue;
            if (c < 64) {
                const int b = (m >= Nn) ? 1 : 0;
                const int n = m - b * Nn;
                xr[(size_t)n * CCOMB + b * FOUTc + c] = acc[nt][r];
            } else {
                outp[(size_t)m * FOUTc + (c - 64)] = acc[nt][r] + bias;
            }
        }
    }
}

// ---------------------------------------------------------------------------
// Edge bucketing: counts -> exclusive scan -> scatter packed (col,val) int2
// into per-row segments.
// ---------------------------------------------------------------------------
__global__ __launch_bounds__(256) void count_rows(
    const int* __restrict__ erow, int* __restrict__ cnt, int E)
{
    const int e = blockIdx.x * 256 + threadIdx.x;
    if (e >= E) return;
    atomicAdd(&cnt[erow[e]], 1);
}

__global__ __launch_bounds__(256) void block_sum(
    const int* __restrict__ cnt, int* __restrict__ bsum)
{
    __shared__ int s[256];
    const int t = threadIdx.x;
    const int idx = blockIdx.x * 256 + t;
    s[t] = (idx < Nn) ? cnt[idx] : 0;
    __syncthreads();
    for (int off = 128; off > 0; off >>= 1) {
        if (t < off) s[t] += s[t + off];
        __syncthreads();
    }
    if (t == 0) bsum[blockIdx.x] = s[0];
}

__global__ __launch_bounds__(256) void scan_bsum(
    const int* __restrict__ bsum, int* __restrict__ bscan, int nb)
{
    __shared__ int s[256];
    const int t = threadIdx.x;
    const int v = (t < nb) ? bsum[t] : 0;
    s[t] = v;
    __syncthreads();
    for (int off = 1; off < 256; off <<= 1) {
        const int add = (t >= off) ? s[t - off] : 0;
        __syncthreads();
        s[t] += add;
        __syncthreads();
    }
    if (t < nb) bscan[t] = s[t] - v;   // exclusive
}

__global__ __launch_bounds__(256) void fill_starts(
    const int* __restrict__ cnt, const int* __restrict__ bscan,
    int* __restrict__ rowstart, int* __restrict__ cursor, int E)
{
    __shared__ int s[256];
    const int t = threadIdx.x;
    const int idx = blockIdx.x * 256 + t;
    const int v = (idx < Nn) ? cnt[idx] : 0;
    s[t] = v;
    __syncthreads();
    for (int off = 1; off < 256; off <<= 1) {
        const int add = (t >= off) ? s[t - off] : 0;
        __syncthreads();
        s[t] += add;
        __syncthreads();
    }
    const int start = bscan[blockIdx.x] + (s[t] - v);
    if (idx < Nn) { rowstart[idx] = start; cursor[idx] = start; }
    if (idx == 0) rowstart[Nn] = E;
}

__global__ __launch_bounds__(256) void bucket(
    const int* __restrict__ erow, const int* __restrict__ ecol,
    const float* __restrict__ evalv, int* __restrict__ cursor,
    int2* __restrict__ cv, int E)
{
    const int e = blockIdx.x * 256 + threadIdx.x;
    if (e >= E) return;
    const int r = erow[e];
    const int pos = atomicAdd(&cursor[r], 1);
    cv[pos] = make_int2(ecol[e], __float_as_int(evalv[e]));
}

// ---------------------------------------------------------------------------
// Per-row gather-reduce fused with finalize. One wave per row.
// Half-wave edge split: lanes 0-31 own edge e, lanes 32-63 edge e+1; each
// half-lane covers 4 of the 128 combined cols (float4). 2x unroll -> 4 edges
// in flight. Epilogue: cross-half shfl combine, lanes 0-31 store float4.
// ---------------------------------------------------------------------------
__global__ __launch_bounds__(256) void row_gather(
    const int* __restrict__ rowstart, const int2* __restrict__ cv,
    const float* __restrict__ xr, float* __restrict__ outp)
{
    const int lane = threadIdx.x & 63;
    int n = blockIdx.x * 4 + (threadIdx.x >> 6);
    n = __builtin_amdgcn_readfirstlane(n);   // wave-uniform -> scalar loads

    const int s    = rowstart[n];
    const int eend = rowstart[n + 1];
    const int sub  = lane >> 5;              // 0/1: which edge of the pair
    const int q    = lane & 31;
    const int c0   = q * 4;

    float4 a = make_float4(0.f, 0.f, 0.f, 0.f);
    float4 b2 = make_float4(0.f, 0.f, 0.f, 0.f);

    int e = s;
    for (; e + 4 <= eend; e += 4) {
        const int2 eA = cv[e + sub];
        const int2 eB = cv[e + 2 + sub];
        const float4 xA = *(const float4*)&xr[(size_t)eA.x * CCOMB + c0];
        const float4 xB = *(const float4*)&xr[(size_t)eB.x * CCOMB + c0];
        const float vA = __int_as_float(eA.y);
        const float vB = __int_as_float(eB.y);
        a.x = fmaf(vA, xA.x, a.x); a.y = fmaf(vA, xA.y, a.y);
        a.z = fmaf(vA, xA.z, a.z); a.w = fmaf(vA, xA.w, a.w);
        b2.x = fmaf(vB, xB.x, b2.x); b2.y = fmaf(vB, xB.y, b2.y);
        b2.z = fmaf(vB, xB.z, b2.z); b2.w = fmaf(vB, xB.w, b2.w);
    }
    if (e + sub < eend) {
        const int2 eA = cv[e + sub];
        const float4 xA = *(const float4*)&xr[(size_t)eA.x * CCOMB + c0];
        const float vA = __int_as_float(eA.y);
        a.x = fmaf(vA, xA.x, a.x); a.y = fmaf(vA, xA.y, a.y);
        a.z = fmaf(vA, xA.z, a.z); a.w = fmaf(vA, xA.w, a.w);
    }
    if (e + 2 + sub < eend) {
        const int2 eB = cv[e + 2 + sub];
        const float4 xB = *(const float4*)&xr[(size_t)eB.x * CCOMB + c0];
        const float vB = __int_as_float(eB.y);
        b2.x = fmaf(vB, xB.x, b2.x); b2.y = fmaf(vB, xB.y, b2.y);
        b2.z = fmaf(vB, xB.z, b2.z); b2.w = fmaf(vB, xB.w, b2.w);
    }
    a.x += b2.x; a.y += b2.y; a.z += b2.z; a.w += b2.w;

    // combine halves: lane L (<32) += lane L+32
    a.x += __shfl_down(a.x, 32);
    a.y += __shfl_down(a.y, 32);
    a.z += __shfl_down(a.z, 32);
    a.w += __shfl_down(a.w, 32);

    if (lane < 32) {
        const int b = c0 >> 6;               // 0 for q<16, 1 for q>=16
        const int o = c0 & 63;
        const size_t oidx = ((size_t)b * Nn + n) * FOUTc + o;
        float4 sp = *(float4*)&outp[oidx];
        sp.x = fmaxf(sp.x + a.x, 0.0f);
        sp.y = fmaxf(sp.y + a.y, 0.0f);
        sp.z = fmaxf(sp.z + a.z, 0.0f);
        sp.w = fmaxf(sp.w + a.w, 0.0f);
        *(float4*)&outp[oidx] = sp;
    }
}

extern "C" void kernel_launch(void* const* d_in, const int* in_sizes, int n_in,
                              void* d_out, int out_size, void* d_ws, size_t ws_size,
                              hipStream_t stream)
{
    const float* x    = (const float*)d_in[0];
    const float* W    = (const float*)d_in[1];
    const float* Ws   = (const float*)d_in[2];
    const float* bs   = (const float*)d_in[3];
    const int*   erow = (const int*)d_in[4];
    const int*   ecol = (const int*)d_in[5];
    const float* eval = (const float*)d_in[6];
    float* outp = (float*)d_out;
    const int E = in_sizes[4];

    // workspace layout
    float* xr       = (float*)d_ws;                     // N*128 f32 = 25.6 MB
    int2*  cv       = (int2*)(xr + (size_t)Nn * CCOMB); // E int2 = 6.4 MB
    int*   rowstart = (int*)(cv + E);                   // N+1
    int*   cursor   = rowstart + (Nn + 2);              // N (doubles as counts)
    int*   bsum     = cursor + Nn;                      // ceil(N/256)
    int*   bscan    = bsum + 256;                       // ceil(N/256)
    unsigned short* Bp = (unsigned short*)(bscan + 256);// 2048*8 bf16 = 32 KB

    const int NB = (Nn + 255) / 256;
    const int EB = (E + 255) / 256;

    // 1. dense: pack weights (bf16 B-fragments), MFMA GEMM
    pack_w<<<8, 256, 0, stream>>>(W, Ws, Bp);
    gemm_mfma<<<(Mtot + 63) / 64, 256, 0, stream>>>(x, Bp, bs, xr, outp);

    // 2. edge bucketing: counts -> scan -> segments
    hipMemsetAsync(cursor, 0, (size_t)Nn * sizeof(int), stream);
    count_rows<<<EB, 256, 0, stream>>>(erow, cursor, E);
    block_sum<<<NB, 256, 0, stream>>>(cursor, bsum);
    scan_bsum<<<1, 256, 0, stream>>>(bsum, bscan, NB);
    fill_starts<<<NB, 256, 0, stream>>>(cursor, bscan, rowstart, cursor, E);
    bucket<<<EB, 256, 0, stream>>>(erow, ecol, eval, cursor, cv, E);

    // 3. per-row gather-reduce fused with self+bias+ReLU finalize
    row_gather<<<Nn / 4, 256, 0, stream>>>(rowstart, cv, xr, outp);
}

// Round 5
// 244.689 us; speedup vs baseline: 6.3015x; 1.1405x over previous
//
#include <hip/hip_runtime.h>

// Problem constants (DirectedGraphLayer): B=2, N=50000, FIN=128, FOUT=64, E=800000
#define Bc   2
#define Nn   50000
#define FINc 128
#define FOUTc 64
#define Mtot (Bc * Nn)          // 100000 combined (b,n) rows
#define CCOMB 128               // combined feature cols: [W cols 0..63 | W_self cols 0..63]
#define GB 1563                 // gemm blocks: ceil(100000/64)
#define CB 782                  // count blocks: ceil(800000/1024)

typedef __bf16 bf16x8 __attribute__((ext_vector_type(8)));
typedef float  f32x4  __attribute__((ext_vector_type(4)));

static __device__ inline unsigned short f2bf(float f) {
    unsigned int u = __float_as_uint(f);
    u += 0x7fffu + ((u >> 16) & 1u);       // round-to-nearest-even
    return (unsigned short)(u >> 16);
}

// ---------------------------------------------------------------------------
// prep: blocks 0..7 pack [W|W_self] into B-fragment-major bf16 (32 KB);
// blocks 8..203 zero the per-row counters.
// Bpack[(nt*4+kt)*64 + lane][j] = Wc[k = kt*32+(lane>>4)*8+j][n = nt*16+(lane&15)]
// ---------------------------------------------------------------------------
__global__ __launch_bounds__(256) void prep(
    const float* __restrict__ W, const float* __restrict__ Ws,
    unsigned short* __restrict__ Bp, int* __restrict__ cnt)
{
    if (blockIdx.x < 8) {
        const int idx = blockIdx.x * 256 + threadIdx.x;
        const int lane = idx & 63;
        const int kt   = (idx >> 6) & 3;
        const int nt   = idx >> 8;
        const int n    = nt * 16 + (lane & 15);
        const int k0   = kt * 32 + (lane >> 4) * 8;
        unsigned short o8[8];
#pragma unroll
        for (int j = 0; j < 8; ++j) {
            const int f = k0 + j;
            const float v = (n < 64) ? W[f * FOUTc + n] : Ws[f * FOUTc + (n - 64)];
            o8[j] = f2bf(v);
        }
        *(uint4*)&Bp[(size_t)idx * 8] = *(uint4*)o8;
    } else {
        const int i = (blockIdx.x - 8) * 256 + threadIdx.x;
        if (i < Nn) cnt[i] = 0;
    }
}

// ---------------------------------------------------------------------------
// gemm_count: blocks [0,GB) = bf16 MFMA GEMM; blocks [GB,GB+CB) = row count.
// GEMM: D(100000x128) = X @ [W|Ws]; cols 0..63 -> xr (bf16, (N,B*64) layout),
// cols 64..127 -> outp pre-ReLU self term (+bias, f32).
// Count part hides its atomic latency under the GEMM's memory streaming.
// ---------------------------------------------------------------------------
__global__ __launch_bounds__(256) void gemm_count(
    const float* __restrict__ x, const unsigned short* __restrict__ Bp,
    const float* __restrict__ bself,
    unsigned short* __restrict__ xrb, float* __restrict__ outp,
    const int* __restrict__ erow, int* __restrict__ cnt, int E)
{
    if (blockIdx.x >= GB) {
        const int base = (blockIdx.x - GB) * 1024 + threadIdx.x * 4;
        if (base + 4 <= E) {
            const int4 r4 = *(const int4*)&erow[base];
            atomicAdd(&cnt[r4.x], 1);
            atomicAdd(&cnt[r4.y], 1);
            atomicAdd(&cnt[r4.z], 1);
            atomicAdd(&cnt[r4.w], 1);
        }
        return;
    }

    const int wave = threadIdx.x >> 6;
    const int lane = threadIdx.x & 63;
    const int quad = lane >> 4;
    const int mbase = blockIdx.x * 64 + wave * 16;

    const int mrow   = mbase + (lane & 15);
    const int mclamp = (mrow < Mtot) ? mrow : (Mtot - 1);
    const float* __restrict__ xrow = &x[(size_t)mclamp * FINc];

    f32x4 acc[8] = {};

#pragma unroll
    for (int kt = 0; kt < 4; ++kt) {
        const int k0 = kt * 32 + quad * 8;
        const float4 xa = *(const float4*)&xrow[k0];
        const float4 xb = *(const float4*)&xrow[k0 + 4];
        bf16x8 af;
        af[0] = (__bf16)xa.x; af[1] = (__bf16)xa.y;
        af[2] = (__bf16)xa.z; af[3] = (__bf16)xa.w;
        af[4] = (__bf16)xb.x; af[5] = (__bf16)xb.y;
        af[6] = (__bf16)xb.z; af[7] = (__bf16)xb.w;

        const bf16x8* __restrict__ bbase =
            (const bf16x8*)&Bp[(size_t)(kt * 64 + lane) * 8];
#pragma unroll
        for (int nt = 0; nt < 8; ++nt) {
            const bf16x8 bfv = bbase[nt * 4 * 64];   // entry (nt*4+kt)*64+lane
            acc[nt] = __builtin_amdgcn_mfma_f32_16x16x32_bf16(af, bfv, acc[nt], 0, 0, 0);
        }
    }

    // epilogue: C/D layout col=lane&15, row=quad*4+reg
    const int col_lo = lane & 15;
#pragma unroll
    for (int nt = 0; nt < 8; ++nt) {
        const int c = nt * 16 + col_lo;
        const float bias = (c >= 64) ? bself[c - 64] : 0.0f;
#pragma unroll
        for (int r = 0; r < 4; ++r) {
            const int m = mbase + quad * 4 + r;
            if (m >= Mtot) continue;
            if (c < 64) {
                const int b = (m >= Nn) ? 1 : 0;
                const int n = m - b * Nn;
                xrb[(size_t)n * CCOMB + b * FOUTc + c] = f2bf(acc[nt][r]);
            } else {
                outp[(size_t)m * FOUTc + (c - 64)] = acc[nt][r] + bias;
            }
        }
    }
}

// ---------------------------------------------------------------------------
// Hierarchical exclusive scan of per-row counts -> rowstart / cursor.
// ---------------------------------------------------------------------------
__global__ __launch_bounds__(256) void block_sum(
    const int* __restrict__ cnt, int* __restrict__ bsum)
{
    __shared__ int s[256];
    const int t = threadIdx.x;
    const int idx = blockIdx.x * 256 + t;
    s[t] = (idx < Nn) ? cnt[idx] : 0;
    __syncthreads();
    for (int off = 128; off > 0; off >>= 1) {
        if (t < off) s[t] += s[t + off];
        __syncthreads();
    }
    if (t == 0) bsum[blockIdx.x] = s[0];
}

__global__ __launch_bounds__(256) void scan_bsum(
    const int* __restrict__ bsum, int* __restrict__ bscan, int nb)
{
    __shared__ int s[256];
    const int t = threadIdx.x;
    const int v = (t < nb) ? bsum[t] : 0;
    s[t] = v;
    __syncthreads();
    for (int off = 1; off < 256; off <<= 1) {
        const int add = (t >= off) ? s[t - off] : 0;
        __syncthreads();
        s[t] += add;
        __syncthreads();
    }
    if (t < nb) bscan[t] = s[t] - v;   // exclusive
}

__global__ __launch_bounds__(256) void fill_starts(
    const int* __restrict__ cnt, const int* __restrict__ bscan,
    int* __restrict__ rowstart, int* __restrict__ cursor, int E)
{
    __shared__ int s[256];
    const int t = threadIdx.x;
    const int idx = blockIdx.x * 256 + t;
    const int v = (idx < Nn) ? cnt[idx] : 0;
    s[t] = v;
    __syncthreads();
    for (int off = 1; off < 256; off <<= 1) {
        const int add = (t >= off) ? s[t - off] : 0;
        __syncthreads();
        s[t] += add;
        __syncthreads();
    }
    const int start = bscan[blockIdx.x] + (s[t] - v);
    if (idx < Nn) { rowstart[idx] = start; cursor[idx] = start; }
    if (idx == 0) rowstart[Nn] = E;
}

// ---------------------------------------------------------------------------
// bucket: scatter packed (col, val) int2 into per-row segments. 4 edges/thread.
// ---------------------------------------------------------------------------
__global__ __launch_bounds__(256) void bucket(
    const int* __restrict__ erow, const int* __restrict__ ecol,
    const float* __restrict__ evalv, int* __restrict__ cursor,
    int2* __restrict__ cv, int E)
{
    const int base = blockIdx.x * 1024 + threadIdx.x * 4;
    if (base + 4 > E) return;
    const int4   r4 = *(const int4*)&erow[base];
    const int4   c4 = *(const int4*)&ecol[base];
    const float4 v4 = *(const float4*)&evalv[base];
    int p;
    p = atomicAdd(&cursor[r4.x], 1); cv[p] = make_int2(c4.x, __float_as_int(v4.x));
    p = atomicAdd(&cursor[r4.y], 1); cv[p] = make_int2(c4.y, __float_as_int(v4.y));
    p = atomicAdd(&cursor[r4.z], 1); cv[p] = make_int2(c4.z, __float_as_int(v4.z));
    p = atomicAdd(&cursor[r4.w], 1); cv[p] = make_int2(c4.w, __float_as_int(v4.w));
}

// ---------------------------------------------------------------------------
// row_gather: one wave per row, bf16 xr. Half-wave edge split (lanes 0-31 own
// even edge of pair, 32-63 odd); each half-lane covers 4 cols via one 8 B
// load (4 bf16). 4x unroll -> 8 edges / 4 independent gathers in flight.
// Fused finalize: out = relu(self_pre + agg).
// ---------------------------------------------------------------------------
#define GATH(EIDX, ACC)                                                     \
    {                                                                       \
        const int2 ev = cv[EIDX];                                           \
        const uint2 raw = *(const uint2*)&xrb[(size_t)ev.x * CCOMB + c0];   \
        const float vv = __int_as_float(ev.y);                              \
        ACC.x = fmaf(vv, __uint_as_float(raw.x << 16), ACC.x);              \
        ACC.y = fmaf(vv, __uint_as_float(raw.x & 0xffff0000u), ACC.y);      \
        ACC.z = fmaf(vv, __uint_as_float(raw.y << 16), ACC.z);              \
        ACC.w = fmaf(vv, __uint_as_float(raw.y & 0xffff0000u), ACC.w);      \
    }

__global__ __launch_bounds__(256) void row_gather(
    const int* __restrict__ rowstart, const int2* __restrict__ cv,
    const unsigned short* __restrict__ xrb, float* __restrict__ outp)
{
    const int lane = threadIdx.x & 63;
    int n = blockIdx.x * 4 + (threadIdx.x >> 6);
    n = __builtin_amdgcn_readfirstlane(n);   // wave-uniform -> scalar loads

    const int s    = rowstart[n];
    const int eend = rowstart[n + 1];
    const int sub  = lane >> 5;              // which edge of each pair
    const int q    = lane & 31;
    const int c0   = q * 4;

    float4 a0 = make_float4(0.f, 0.f, 0.f, 0.f);
    float4 a1 = make_float4(0.f, 0.f, 0.f, 0.f);
    float4 a2 = make_float4(0.f, 0.f, 0.f, 0.f);
    float4 a3 = make_float4(0.f, 0.f, 0.f, 0.f);

    int e = s;
    for (; e + 8 <= eend; e += 8) {
        GATH(e + sub,     a0);
        GATH(e + 2 + sub, a1);
        GATH(e + 4 + sub, a2);
        GATH(e + 6 + sub, a3);
    }
    if (e + 4 <= eend) {
        GATH(e + sub,     a0);
        GATH(e + 2 + sub, a1);
        e += 4;
    }
    for (; e + sub < eend; e += 2) {
        GATH(e + sub, a2);
    }

    a0.x += a1.x + a2.x + a3.x;
    a0.y += a1.y + a2.y + a3.y;
    a0.z += a1.z + a2.z + a3.z;
    a0.w += a1.w + a2.w + a3.w;

    // combine halves: lane L (<32) += lane L+32
    a0.x += __shfl_down(a0.x, 32);
    a0.y += __shfl_down(a0.y, 32);
    a0.z += __shfl_down(a0.z, 32);
    a0.w += __shfl_down(a0.w, 32);

    if (lane < 32) {
        const int b = c0 >> 6;
        const int o = c0 & 63;
        const size_t oidx = ((size_t)b * Nn + n) * FOUTc + o;
        float4 sp = *(float4*)&outp[oidx];
        sp.x = fmaxf(sp.x + a0.x, 0.0f);
        sp.y = fmaxf(sp.y + a0.y, 0.0f);
        sp.z = fmaxf(sp.z + a0.z, 0.0f);
        sp.w = fmaxf(sp.w + a0.w, 0.0f);
        *(float4*)&outp[oidx] = sp;
    }
}

extern "C" void kernel_launch(void* const* d_in, const int* in_sizes, int n_in,
                              void* d_out, int out_size, void* d_ws, size_t ws_size,
                              hipStream_t stream)
{
    const float* x    = (const float*)d_in[0];
    const float* W    = (const float*)d_in[1];
    const float* Ws   = (const float*)d_in[2];
    const float* bs   = (const float*)d_in[3];
    const int*   erow = (const int*)d_in[4];
    const int*   ecol = (const int*)d_in[5];
    const float* eval = (const float*)d_in[6];
    float* outp = (float*)d_out;
    const int E = in_sizes[4];

    // workspace layout (all 16 B aligned)
    unsigned short* xrb = (unsigned short*)d_ws;        // N*128 bf16 = 12.8 MB
    int2* cv       = (int2*)(xrb + (size_t)Nn * CCOMB); // E int2 = 6.4 MB
    int*  rowstart = (int*)(cv + E);                    // N+1 (+pad to 16B)
    int*  cursor   = rowstart + (Nn + 4);               // N (doubles as counts)
    int*  bsum     = cursor + Nn;                       // 256
    int*  bscan    = bsum + 256;                        // 256
    unsigned short* Bp = (unsigned short*)(bscan + 256);// 2048*8 bf16 = 32 KB

    const int NB = (Nn + 255) / 256;   // 196

    // 1. pack weights + zero counters
    prep<<<8 + NB, 256, 0, stream>>>(W, Ws, Bp, cursor);

    // 2. GEMM (xr bf16 + self term) fused with edge row counting
    gemm_count<<<GB + CB, 256, 0, stream>>>(x, Bp, bs, xrb, outp, erow, cursor, E);

    // 3. scan counts -> segment starts
    block_sum<<<NB, 256, 0, stream>>>(cursor, bsum);
    scan_bsum<<<1, 256, 0, stream>>>(bsum, bscan, NB);
    fill_starts<<<NB, 256, 0, stream>>>(cursor, bscan, rowstart, cursor, E);

    // 4. scatter (col,val) into per-row segments
    bucket<<<CB, 256, 0, stream>>>(erow, ecol, eval, cursor, cv, E);

    // 5. per-row gather-reduce fused with self+bias+ReLU finalize
    row_gather<<<Nn / 4, 256, 0, stream>>>(rowstart, cv, xrb, outp);
}

// Round 6
// 212.887 us; speedup vs baseline: 7.2428x; 1.1494x over previous
//
#include <hip/hip_runtime.h>
#include <hip/hip_fp16.h>

// Problem constants (DirectedGraphLayer): B=2, N=50000, FIN=128, FOUT=64, E=800000
#define Bc   2
#define Nn   50000
#define FINc 128
#define FOUTc 64
#define Mtot (Bc * Nn)          // 100000 combined (b,n) rows
#define CCOMB 128               // combined feature cols: [W cols 0..63 | W_self cols 0..63]
#define GB 1563                 // gemm blocks: ceil(100000/64)
#define CB 782                  // count blocks: ceil(800000/1024)

typedef __bf16 bf16x8 __attribute__((ext_vector_type(8)));
typedef float  f32x4  __attribute__((ext_vector_type(4)));

static __device__ inline unsigned short f2bf(float f) {
    unsigned int u = __float_as_uint(f);
    u += 0x7fffu + ((u >> 16) & 1u);       // round-to-nearest-even
    return (unsigned short)(u >> 16);
}

// ---------------------------------------------------------------------------
// pack_w: [W|W_self] -> B-fragment-major bf16 (32 KB).
// Bpack[(nt*4+kt)*64 + lane][j] = Wc[k = kt*32+(lane>>4)*8+j][n = nt*16+(lane&15)]
// ---------------------------------------------------------------------------
__global__ __launch_bounds__(256) void pack_w(
    const float* __restrict__ W, const float* __restrict__ Ws,
    unsigned short* __restrict__ Bp)
{
    const int idx = blockIdx.x * 256 + threadIdx.x;
    const int lane = idx & 63;
    const int kt   = (idx >> 6) & 3;
    const int nt   = idx >> 8;
    const int n    = nt * 16 + (lane & 15);
    const int k0   = kt * 32 + (lane >> 4) * 8;
    unsigned short o8[8];
#pragma unroll
    for (int j = 0; j < 8; ++j) {
        const int f = k0 + j;
        const float v = (n < 64) ? W[f * FOUTc + n] : Ws[f * FOUTc + (n - 64)];
        o8[j] = f2bf(v);
    }
    *(uint4*)&Bp[(size_t)idx * 8] = *(uint4*)o8;
}

// ---------------------------------------------------------------------------
// gemm_count: blocks [0,GB) = bf16 MFMA GEMM; blocks [GB,GB+CB) = row count.
// Count uses LINE-PADDED counters (cntp[row*16], 64 B apart -> no same-line
// RMW serialization) and records each edge's rank (atomic return) so the
// bucket pass needs no atomics at all.
// ---------------------------------------------------------------------------
__global__ __launch_bounds__(256) void gemm_count(
    const float* __restrict__ x, const unsigned short* __restrict__ Bp,
    const float* __restrict__ bself,
    unsigned short* __restrict__ xrb, float* __restrict__ outp,
    const int* __restrict__ erow, int* __restrict__ cntp,
    int* __restrict__ rank, int E)
{
    if (blockIdx.x >= GB) {
        const int base = (blockIdx.x - GB) * 1024 + threadIdx.x * 4;
        if (base + 4 <= E) {
            const int4 r4 = *(const int4*)&erow[base];
            const int k0 = atomicAdd(&cntp[(size_t)r4.x * 16], 1);
            const int k1 = atomicAdd(&cntp[(size_t)r4.y * 16], 1);
            const int k2 = atomicAdd(&cntp[(size_t)r4.z * 16], 1);
            const int k3 = atomicAdd(&cntp[(size_t)r4.w * 16], 1);
            *(int4*)&rank[base] = make_int4(k0, k1, k2, k3);
        }
        return;
    }

    const int wave = threadIdx.x >> 6;
    const int lane = threadIdx.x & 63;
    const int quad = lane >> 4;
    const int mbase = blockIdx.x * 64 + wave * 16;

    const int mrow   = mbase + (lane & 15);
    const int mclamp = (mrow < Mtot) ? mrow : (Mtot - 1);
    const float* __restrict__ xrow = &x[(size_t)mclamp * FINc];

    f32x4 acc[8] = {};

#pragma unroll
    for (int kt = 0; kt < 4; ++kt) {
        const int k0 = kt * 32 + quad * 8;
        const float4 xa = *(const float4*)&xrow[k0];
        const float4 xb = *(const float4*)&xrow[k0 + 4];
        bf16x8 af;
        af[0] = (__bf16)xa.x; af[1] = (__bf16)xa.y;
        af[2] = (__bf16)xa.z; af[3] = (__bf16)xa.w;
        af[4] = (__bf16)xb.x; af[5] = (__bf16)xb.y;
        af[6] = (__bf16)xb.z; af[7] = (__bf16)xb.w;

        const bf16x8* __restrict__ bbase =
            (const bf16x8*)&Bp[(size_t)(kt * 64 + lane) * 8];
#pragma unroll
        for (int nt = 0; nt < 8; ++nt) {
            const bf16x8 bfv = bbase[nt * 4 * 64];   // entry (nt*4+kt)*64+lane
            acc[nt] = __builtin_amdgcn_mfma_f32_16x16x32_bf16(af, bfv, acc[nt], 0, 0, 0);
        }
    }

    // epilogue: C/D layout col=lane&15, row=quad*4+reg
    const int col_lo = lane & 15;
#pragma unroll
    for (int nt = 0; nt < 8; ++nt) {
        const int c = nt * 16 + col_lo;
        const float bias = (c >= 64) ? bself[c - 64] : 0.0f;
#pragma unroll
        for (int r = 0; r < 4; ++r) {
            const int m = mbase + quad * 4 + r;
            if (m >= Mtot) continue;
            if (c < 64) {
                const int b = (m >= Nn) ? 1 : 0;
                const int n = m - b * Nn;
                xrb[(size_t)n * CCOMB + b * FOUTc + c] = f2bf(acc[nt][r]);
            } else {
                outp[(size_t)m * FOUTc + (c - 64)] = acc[nt][r] + bias;
            }
        }
    }
}

// ---------------------------------------------------------------------------
// Hierarchical exclusive scan of padded counts -> rowstart.
// ---------------------------------------------------------------------------
__global__ __launch_bounds__(256) void block_sum(
    const int* __restrict__ cntp, int* __restrict__ bsum)
{
    __shared__ int s[256];
    const int t = threadIdx.x;
    const int idx = blockIdx.x * 256 + t;
    s[t] = (idx < Nn) ? cntp[(size_t)idx * 16] : 0;
    __syncthreads();
    for (int off = 128; off > 0; off >>= 1) {
        if (t < off) s[t] += s[t + off];
        __syncthreads();
    }
    if (t == 0) bsum[blockIdx.x] = s[0];
}

__global__ __launch_bounds__(256) void scan_bsum(
    const int* __restrict__ bsum, int* __restrict__ bscan, int nb)
{
    __shared__ int s[256];
    const int t = threadIdx.x;
    const int v = (t < nb) ? bsum[t] : 0;
    s[t] = v;
    __syncthreads();
    for (int off = 1; off < 256; off <<= 1) {
        const int add = (t >= off) ? s[t - off] : 0;
        __syncthreads();
        s[t] += add;
        __syncthreads();
    }
    if (t < nb) bscan[t] = s[t] - v;   // exclusive
}

__global__ __launch_bounds__(256) void fill_starts(
    const int* __restrict__ cntp, const int* __restrict__ bscan,
    int* __restrict__ rowstart, int E)
{
    __shared__ int s[256];
    const int t = threadIdx.x;
    const int idx = blockIdx.x * 256 + t;
    const int v = (idx < Nn) ? cntp[(size_t)idx * 16] : 0;
    s[t] = v;
    __syncthreads();
    for (int off = 1; off < 256; off <<= 1) {
        const int add = (t >= off) ? s[t - off] : 0;
        __syncthreads();
        s[t] += add;
        __syncthreads();
    }
    if (idx < Nn) rowstart[idx] = bscan[blockIdx.x] + (s[t] - v);
    if (idx == 0) rowstart[Nn] = E;
}

// ---------------------------------------------------------------------------
// bucket: NO atomics. pos = rowstart[row] + rank[e]; store packed 4 B
// (fp16 val without sign bit, 15 bits) << 17 | col (17 bits).
// ---------------------------------------------------------------------------
__global__ __launch_bounds__(256) void bucket(
    const int* __restrict__ erow, const int* __restrict__ ecol,
    const float* __restrict__ evalv, const int* __restrict__ rank,
    const int* __restrict__ rowstart, unsigned int* __restrict__ cvp, int E)
{
    const int e = blockIdx.x * 512 + threadIdx.x * 2;
    if (e + 2 > E) return;
    const int2   r2 = *(const int2*)&erow[e];
    const int2   c2 = *(const int2*)&ecol[e];
    const float2 v2 = *(const float2*)&evalv[e];
    const int2   k2 = *(const int2*)&rank[e];
    const unsigned int h0 = __half_as_ushort(__float2half(v2.x));  // val>=0 -> 15 bits
    const unsigned int h1 = __half_as_ushort(__float2half(v2.y));
    cvp[rowstart[r2.x] + k2.x] = (h0 << 17) | (unsigned int)c2.x;
    cvp[rowstart[r2.y] + k2.y] = (h1 << 17) | (unsigned int)c2.y;
}

// ---------------------------------------------------------------------------
// row_gather: one wave per row. 16 lanes per edge (4 edge-slots/wave); each
// lane covers 8 cols via one 16 B load of 8 bf16. 2x unroll -> 8 edges in
// flight. Epilogue: 2-round shfl reduce, lanes 0-15 store 32 B each.
// Fused finalize: out = relu(self_pre + agg).
// ---------------------------------------------------------------------------
#define GATH16(EIDX, ACC)                                                     \
    {                                                                         \
        const unsigned int w = cvp[EIDX];                                     \
        const float vv = __half2float(__ushort_as_half(                       \
                             (unsigned short)(w >> 17)));                     \
        const uint4 raw = *(const uint4*)&xrb[(size_t)(w & 0x1FFFFu) * CCOMB + c0]; \
        ACC[0] = fmaf(vv, __uint_as_float(raw.x << 16),         ACC[0]);      \
        ACC[1] = fmaf(vv, __uint_as_float(raw.x & 0xffff0000u), ACC[1]);      \
        ACC[2] = fmaf(vv, __uint_as_float(raw.y << 16),         ACC[2]);      \
        ACC[3] = fmaf(vv, __uint_as_float(raw.y & 0xffff0000u), ACC[3]);      \
        ACC[4] = fmaf(vv, __uint_as_float(raw.z << 16),         ACC[4]);      \
        ACC[5] = fmaf(vv, __uint_as_float(raw.z & 0xffff0000u), ACC[5]);      \
        ACC[6] = fmaf(vv, __uint_as_float(raw.w << 16),         ACC[6]);      \
        ACC[7] = fmaf(vv, __uint_as_float(raw.w & 0xffff0000u), ACC[7]);      \
    }

__global__ __launch_bounds__(256) void row_gather(
    const int* __restrict__ rowstart, const unsigned int* __restrict__ cvp,
    const unsigned short* __restrict__ xrb, float* __restrict__ outp)
{
    const int lane = threadIdx.x & 63;
    int n = blockIdx.x * 4 + (threadIdx.x >> 6);
    n = __builtin_amdgcn_readfirstlane(n);   // wave-uniform -> scalar loads

    const int s    = rowstart[n];
    const int eend = rowstart[n + 1];
    const int sub  = lane >> 4;              // edge slot 0..3
    const int c0   = (lane & 15) * 8;        // 8 combined cols per lane

    float aA[8] = {0.f, 0.f, 0.f, 0.f, 0.f, 0.f, 0.f, 0.f};
    float aB[8] = {0.f, 0.f, 0.f, 0.f, 0.f, 0.f, 0.f, 0.f};

    int e = s;
    for (; e + 8 <= eend; e += 8) {
        GATH16(e + sub,     aA);
        GATH16(e + 4 + sub, aB);
    }
    for (; e < eend; e += 4) {
        if (e + sub < eend) GATH16(e + sub, aA);
    }

#pragma unroll
    for (int i = 0; i < 8; ++i) {
        aA[i] += aB[i];
        aA[i] += __shfl_down(aA[i], 16);
        aA[i] += __shfl_down(aA[i], 32);
    }

    if (lane < 16) {
        const int b = c0 >> 6;               // cols 0..63 -> b0, 64..127 -> b1
        const int o = c0 & 63;
        const size_t oidx = ((size_t)b * Nn + n) * FOUTc + o;
        float4 s0 = *(float4*)&outp[oidx];
        float4 s1 = *(float4*)&outp[oidx + 4];
        s0.x = fmaxf(s0.x + aA[0], 0.0f);
        s0.y = fmaxf(s0.y + aA[1], 0.0f);
        s0.z = fmaxf(s0.z + aA[2], 0.0f);
        s0.w = fmaxf(s0.w + aA[3], 0.0f);
        s1.x = fmaxf(s1.x + aA[4], 0.0f);
        s1.y = fmaxf(s1.y + aA[5], 0.0f);
        s1.z = fmaxf(s1.z + aA[6], 0.0f);
        s1.w = fmaxf(s1.w + aA[7], 0.0f);
        *(float4*)&outp[oidx]     = s0;
        *(float4*)&outp[oidx + 4] = s1;
    }
}

extern "C" void kernel_launch(void* const* d_in, const int* in_sizes, int n_in,
                              void* d_out, int out_size, void* d_ws, size_t ws_size,
                              hipStream_t stream)
{
    const float* x    = (const float*)d_in[0];
    const float* W    = (const float*)d_in[1];
    const float* Ws   = (const float*)d_in[2];
    const float* bs   = (const float*)d_in[3];
    const int*   erow = (const int*)d_in[4];
    const int*   ecol = (const int*)d_in[5];
    const float* eval = (const float*)d_in[6];
    float* outp = (float*)d_out;
    const int E = in_sizes[4];

    // workspace layout (every base 16 B aligned by construction)
    unsigned short* xrb = (unsigned short*)d_ws;         // N*128 bf16 = 12.8 MB
    unsigned int* cvp = (unsigned int*)(xrb + (size_t)Nn * CCOMB); // E u32 = 3.2 MB
    int* rank     = (int*)(cvp + E);                     // E ints = 3.2 MB
    int* rowstart = rank + E;                            // N+1 (+pad)
    int* cntp     = rowstart + (Nn + 4);                 // N*16 ints (line-padded) = 3.2 MB
    int* bsum     = cntp + (size_t)Nn * 16;              // 256
    int* bscan    = bsum + 256;                          // 256
    unsigned short* Bp = (unsigned short*)(bscan + 256); // 2048*8 bf16 = 32 KB

    const int NB = (Nn + 255) / 256;   // 196

    // 1. zero padded counters; pack weights
    hipMemsetAsync(cntp, 0, (size_t)Nn * 16 * sizeof(int), stream);
    pack_w<<<8, 256, 0, stream>>>(W, Ws, Bp);

    // 2. GEMM (xrb bf16 + self term) fused with padded-atomic count + rank
    gemm_count<<<GB + CB, 256, 0, stream>>>(x, Bp, bs, xrb, outp,
                                            erow, cntp, rank, E);

    // 3. scan counts -> segment starts
    block_sum<<<NB, 256, 0, stream>>>(cntp, bsum);
    scan_bsum<<<1, 256, 0, stream>>>(bsum, bscan, NB);
    fill_starts<<<NB, 256, 0, stream>>>(cntp, bscan, rowstart, E);

    // 4. atomic-free scatter of packed (val,col) into per-row segments
    bucket<<<(E + 511) / 512, 256, 0, stream>>>(erow, ecol, eval, rank,
                                                rowstart, cvp, E);

    // 5. per-row gather-reduce fused with self+bias+ReLU finalize
    row_gather<<<Nn / 4, 256, 0, stream>>>(rowstart, cvp, xrb, outp);
}

// Round 7
// 209.000 us; speedup vs baseline: 7.3775x; 1.0186x over previous
//
#include <hip/hip_runtime.h>
#include <hip/hip_fp16.h>

// Problem constants (DirectedGraphLayer): B=2, N=50000, FIN=128, FOUT=64, E=800000
#define Bc   2
#define Nn   50000
#define FINc 128
#define FOUTc 64
#define Mtot (Bc * Nn)          // 100000 combined (b,n) rows
#define CCOMB 128               // combined feature cols: [W cols 0..63 | W_self cols 0..63]
#define GB 1563                 // gemm blocks: ceil(100000/64)
#define CB 782                  // count blocks: ceil(800000/1024)

typedef __bf16 bf16x8 __attribute__((ext_vector_type(8)));
typedef float  f32x4  __attribute__((ext_vector_type(4)));

static __device__ inline unsigned short f2bf(float f) {
    unsigned int u = __float_as_uint(f);
    u += 0x7fffu + ((u >> 16) & 1u);       // round-to-nearest-even
    return (unsigned short)(u >> 16);
}

// ---------------------------------------------------------------------------
// pack_w: [W|W_self] -> fragment-major bf16 (32 KB).  Used as the MFMA *A*
// operand (A[m=o][k]): entry (nt*4+kt)*64+lane holds
//   Wc[k = kt*32+(lane>>4)*8+j][o = nt*16+(lane&15)],  j=0..7
// which is exactly A-layout m=lane&15, k=quad*8+j for tile (nt,kt).
// ---------------------------------------------------------------------------
__global__ __launch_bounds__(256) void pack_w(
    const float* __restrict__ W, const float* __restrict__ Ws,
    unsigned short* __restrict__ Bp)
{
    const int idx = blockIdx.x * 256 + threadIdx.x;
    const int lane = idx & 63;
    const int kt   = (idx >> 6) & 3;
    const int nt   = idx >> 8;
    const int n    = nt * 16 + (lane & 15);
    const int k0   = kt * 32 + (lane >> 4) * 8;
    unsigned short o8[8];
#pragma unroll
    for (int j = 0; j < 8; ++j) {
        const int f = k0 + j;
        const float v = (n < 64) ? W[f * FOUTc + n] : Ws[f * FOUTc + (n - 64)];
        o8[j] = f2bf(v);
    }
    *(uint4*)&Bp[(size_t)idx * 8] = *(uint4*)o8;
}

// ---------------------------------------------------------------------------
// gemm_count: blocks [0,GB) = bf16 MFMA GEMM (swapped operands: D = W^T x^T);
// blocks [GB,GB+CB) = padded-atomic row count + per-edge rank.
//
// Swapped-operand layout: D[row=o_local=quad*4+reg][col=m_local=lane&15].
// => each lane owns ONE output row m and 4 CONSECUTIVE features per nt-tile:
//    o = nt*16 + quad*4 + reg.  Epilogue is 8 wide stores per lane.
// ---------------------------------------------------------------------------
__global__ __launch_bounds__(256) void gemm_count(
    const float* __restrict__ x, const unsigned short* __restrict__ Bp,
    const float* __restrict__ bself,
    unsigned short* __restrict__ xrb, float* __restrict__ outp,
    const int* __restrict__ erow, int* __restrict__ cntp,
    int* __restrict__ rank, int E)
{
    if (blockIdx.x >= GB) {
        const int base = (blockIdx.x - GB) * 1024 + threadIdx.x * 4;
        if (base + 4 <= E) {
            const int4 r4 = *(const int4*)&erow[base];
            const int k0 = atomicAdd(&cntp[(size_t)r4.x * 16], 1);
            const int k1 = atomicAdd(&cntp[(size_t)r4.y * 16], 1);
            const int k2 = atomicAdd(&cntp[(size_t)r4.z * 16], 1);
            const int k3 = atomicAdd(&cntp[(size_t)r4.w * 16], 1);
            *(int4*)&rank[base] = make_int4(k0, k1, k2, k3);
        }
        return;
    }

    const int wave = threadIdx.x >> 6;
    const int lane = threadIdx.x & 63;
    const int quad = lane >> 4;
    const int mbase = blockIdx.x * 64 + wave * 16;

    const int mrow   = mbase + (lane & 15);
    const int mclamp = (mrow < Mtot) ? mrow : (Mtot - 1);
    const float* __restrict__ xrow = &x[(size_t)mclamp * FINc];

    f32x4 acc[8] = {};

#pragma unroll
    for (int kt = 0; kt < 4; ++kt) {
        const int k0 = kt * 32 + quad * 8;
        const float4 xa = *(const float4*)&xrow[k0];
        const float4 xb = *(const float4*)&xrow[k0 + 4];
        bf16x8 bf;                       // B operand: B[k][m], m=lane&15
        bf[0] = (__bf16)xa.x; bf[1] = (__bf16)xa.y;
        bf[2] = (__bf16)xa.z; bf[3] = (__bf16)xa.w;
        bf[4] = (__bf16)xb.x; bf[5] = (__bf16)xb.y;
        bf[6] = (__bf16)xb.z; bf[7] = (__bf16)xb.w;

        const bf16x8* __restrict__ abase =
            (const bf16x8*)&Bp[(size_t)(kt * 64 + lane) * 8];
#pragma unroll
        for (int nt = 0; nt < 8; ++nt) {
            const bf16x8 af = abase[nt * 4 * 64];   // entry (nt*4+kt)*64+lane
            // swapped: A = weights (m-index = feature o), B = x (n-index = row m)
            acc[nt] = __builtin_amdgcn_mfma_f32_16x16x32_bf16(af, bf, acc[nt], 0, 0, 0);
        }
    }

    // epilogue: lane owns row m = mbase+(lane&15); per nt, 4 consecutive
    // features o = nt*16 + quad*4 + (0..3).
    const int m = mbase + (lane & 15);
    if (m < Mtot) {
        const int b = (m >= Nn) ? 1 : 0;
        const int n = m - b * Nn;
        unsigned short* __restrict__ xp = &xrb[(size_t)n * CCOMB + b * FOUTc];
        const int cq = quad * 4;
#pragma unroll
        for (int nt = 0; nt < 4; ++nt) {
            const int c = nt * 16 + cq;             // 0..63, multiple of 4
            unsigned short h[4];
            h[0] = f2bf(acc[nt][0]); h[1] = f2bf(acc[nt][1]);
            h[2] = f2bf(acc[nt][2]); h[3] = f2bf(acc[nt][3]);
            *(uint2*)&xp[c] = *(uint2*)h;           // 8 B store
        }
        float* __restrict__ op = &outp[(size_t)m * FOUTc];
#pragma unroll
        for (int nt = 4; nt < 8; ++nt) {
            const int o = (nt - 4) * 16 + cq;       // 0..63, multiple of 4
            const float4 b4 = *(const float4*)&bself[o];   // quad-broadcast
            float4 v;
            v.x = acc[nt][0] + b4.x; v.y = acc[nt][1] + b4.y;
            v.z = acc[nt][2] + b4.z; v.w = acc[nt][3] + b4.w;
            *(float4*)&op[o] = v;                   // 16 B store, line-dense
        }
    }
}

// ---------------------------------------------------------------------------
// Hierarchical exclusive scan of padded counts -> rowstart.
// ---------------------------------------------------------------------------
__global__ __launch_bounds__(256) void block_sum(
    const int* __restrict__ cntp, int* __restrict__ bsum)
{
    __shared__ int s[256];
    const int t = threadIdx.x;
    const int idx = blockIdx.x * 256 + t;
    s[t] = (idx < Nn) ? cntp[(size_t)idx * 16] : 0;
    __syncthreads();
    for (int off = 128; off > 0; off >>= 1) {
        if (t < off) s[t] += s[t + off];
        __syncthreads();
    }
    if (t == 0) bsum[blockIdx.x] = s[0];
}

__global__ __launch_bounds__(256) void scan_bsum(
    const int* __restrict__ bsum, int* __restrict__ bscan, int nb)
{
    __shared__ int s[256];
    const int t = threadIdx.x;
    const int v = (t < nb) ? bsum[t] : 0;
    s[t] = v;
    __syncthreads();
    for (int off = 1; off < 256; off <<= 1) {
        const int add = (t >= off) ? s[t - off] : 0;
        __syncthreads();
        s[t] += add;
        __syncthreads();
    }
    if (t < nb) bscan[t] = s[t] - v;   // exclusive
}

__global__ __launch_bounds__(256) void fill_starts(
    const int* __restrict__ cntp, const int* __restrict__ bscan,
    int* __restrict__ rowstart, int E)
{
    __shared__ int s[256];
    const int t = threadIdx.x;
    const int idx = blockIdx.x * 256 + t;
    const int v = (idx < Nn) ? cntp[(size_t)idx * 16] : 0;
    s[t] = v;
    __syncthreads();
    for (int off = 1; off < 256; off <<= 1) {
        const int add = (t >= off) ? s[t - off] : 0;
        __syncthreads();
        s[t] += add;
        __syncthreads();
    }
    if (idx < Nn) rowstart[idx] = bscan[blockIdx.x] + (s[t] - v);
    if (idx == 0) rowstart[Nn] = E;
}

// ---------------------------------------------------------------------------
// bucket: NO atomics. pos = rowstart[row] + rank[e]; store packed 4 B
// (fp16 val without sign bit, 15 bits) << 17 | col (17 bits).
// ---------------------------------------------------------------------------
__global__ __launch_bounds__(256) void bucket(
    const int* __restrict__ erow, const int* __restrict__ ecol,
    const float* __restrict__ evalv, const int* __restrict__ rank,
    const int* __restrict__ rowstart, unsigned int* __restrict__ cvp, int E)
{
    const int e = blockIdx.x * 512 + threadIdx.x * 2;
    if (e + 2 > E) return;
    const int2   r2 = *(const int2*)&erow[e];
    const int2   c2 = *(const int2*)&ecol[e];
    const float2 v2 = *(const float2*)&evalv[e];
    const int2   k2 = *(const int2*)&rank[e];
    const unsigned int h0 = __half_as_ushort(__float2half(v2.x));  // val>=0 -> 15 bits
    const unsigned int h1 = __half_as_ushort(__float2half(v2.y));
    cvp[rowstart[r2.x] + k2.x] = (h0 << 17) | (unsigned int)c2.x;
    cvp[rowstart[r2.y] + k2.y] = (h1 << 17) | (unsigned int)c2.y;
}

// ---------------------------------------------------------------------------
// row_gather: one wave per row. 16 lanes per edge (4 edge-slots/wave); each
// lane covers 8 cols via one 16 B load of 8 bf16. 2x unroll -> 8 edges in
// flight. Epilogue: 2-round shfl reduce, lanes 0-15 store 32 B each.
// Fused finalize: out = relu(self_pre + agg).
// ---------------------------------------------------------------------------
#define GATH16(EIDX, ACC)                                                     \
    {                                                                         \
        const unsigned int w = cvp[EIDX];                                     \
        const float vv = __half2float(__ushort_as_half(                       \
                             (unsigned short)(w >> 17)));                     \
        const uint4 raw = *(const uint4*)&xrb[(size_t)(w & 0x1FFFFu) * CCOMB + c0]; \
        ACC[0] = fmaf(vv, __uint_as_float(raw.x << 16),         ACC[0]);      \
        ACC[1] = fmaf(vv, __uint_as_float(raw.x & 0xffff0000u), ACC[1]);      \
        ACC[2] = fmaf(vv, __uint_as_float(raw.y << 16),         ACC[2]);      \
        ACC[3] = fmaf(vv, __uint_as_float(raw.y & 0xffff0000u), ACC[3]);      \
        ACC[4] = fmaf(vv, __uint_as_float(raw.z << 16),         ACC[4]);      \
        ACC[5] = fmaf(vv, __uint_as_float(raw.z & 0xffff0000u), ACC[5]);      \
        ACC[6] = fmaf(vv, __uint_as_float(raw.w << 16),         ACC[6]);      \
        ACC[7] = fmaf(vv, __uint_as_float(raw.w & 0xffff0000u), ACC[7]);      \
    }

__global__ __launch_bounds__(256) void row_gather(
    const int* __restrict__ rowstart, const unsigned int* __restrict__ cvp,
    const unsigned short* __restrict__ xrb, float* __restrict__ outp)
{
    const int lane = threadIdx.x & 63;
    int n = blockIdx.x * 4 + (threadIdx.x >> 6);
    n = __builtin_amdgcn_readfirstlane(n);   // wave-uniform -> scalar loads

    const int s    = rowstart[n];
    const int eend = rowstart[n + 1];
    const int sub  = lane >> 4;              // edge slot 0..3
    const int c0   = (lane & 15) * 8;        // 8 combined cols per lane

    float aA[8] = {0.f, 0.f, 0.f, 0.f, 0.f, 0.f, 0.f, 0.f};
    float aB[8] = {0.f, 0.f, 0.f, 0.f, 0.f, 0.f, 0.f, 0.f};

    int e = s;
    for (; e + 8 <= eend; e += 8) {
        GATH16(e + sub,     aA);
        GATH16(e + 4 + sub, aB);
    }
    for (; e < eend; e += 4) {
        if (e + sub < eend) GATH16(e + sub, aA);
    }

#pragma unroll
    for (int i = 0; i < 8; ++i) {
        aA[i] += aB[i];
        aA[i] += __shfl_down(aA[i], 16);
        aA[i] += __shfl_down(aA[i], 32);
    }

    if (lane < 16) {
        const int b = c0 >> 6;               // cols 0..63 -> b0, 64..127 -> b1
        const int o = c0 & 63;
        const size_t oidx = ((size_t)b * Nn + n) * FOUTc + o;
        float4 s0 = *(float4*)&outp[oidx];
        float4 s1 = *(float4*)&outp[oidx + 4];
        s0.x = fmaxf(s0.x + aA[0], 0.0f);
        s0.y = fmaxf(s0.y + aA[1], 0.0f);
        s0.z = fmaxf(s0.z + aA[2], 0.0f);
        s0.w = fmaxf(s0.w + aA[3], 0.0f);
        s1.x = fmaxf(s1.x + aA[4], 0.0f);
        s1.y = fmaxf(s1.y + aA[5], 0.0f);
        s1.z = fmaxf(s1.z + aA[6], 0.0f);
        s1.w = fmaxf(s1.w + aA[7], 0.0f);
        *(float4*)&outp[oidx]     = s0;
        *(float4*)&outp[oidx + 4] = s1;
    }
}

extern "C" void kernel_launch(void* const* d_in, const int* in_sizes, int n_in,
                              void* d_out, int out_size, void* d_ws, size_t ws_size,
                              hipStream_t stream)
{
    const float* x    = (const float*)d_in[0];
    const float* W    = (const float*)d_in[1];
    const float* Ws   = (const float*)d_in[2];
    const float* bs   = (const float*)d_in[3];
    const int*   erow = (const int*)d_in[4];
    const int*   ecol = (const int*)d_in[5];
    const float* eval = (const float*)d_in[6];
    float* outp = (float*)d_out;
    const int E = in_sizes[4];

    // workspace layout (every base 16 B aligned by construction)
    unsigned short* xrb = (unsigned short*)d_ws;         // N*128 bf16 = 12.8 MB
    unsigned int* cvp = (unsigned int*)(xrb + (size_t)Nn * CCOMB); // E u32 = 3.2 MB
    int* rank     = (int*)(cvp + E);                     // E ints = 3.2 MB
    int* rowstart = rank + E;                            // N+1 (+pad)
    int* cntp     = rowstart + (Nn + 4);                 // N*16 ints (line-padded) = 3.2 MB
    int* bsum     = cntp + (size_t)Nn * 16;              // 256
    int* bscan    = bsum + 256;                          // 256
    unsigned short* Bp = (unsigned short*)(bscan + 256); // 2048*8 bf16 = 32 KB

    const int NB = (Nn + 255) / 256;   // 196

    // 1. zero padded counters; pack weights
    hipMemsetAsync(cntp, 0, (size_t)Nn * 16 * sizeof(int), stream);
    pack_w<<<8, 256, 0, stream>>>(W, Ws, Bp);

    // 2. GEMM (swapped-operand MFMA, wide epilogue) fused with count + rank
    gemm_count<<<GB + CB, 256, 0, stream>>>(x, Bp, bs, xrb, outp,
                                            erow, cntp, rank, E);

    // 3. scan counts -> segment starts
    block_sum<<<NB, 256, 0, stream>>>(cntp, bsum);
    scan_bsum<<<1, 256, 0, stream>>>(bsum, bscan, NB);
    fill_starts<<<NB, 256, 0, stream>>>(cntp, bscan, rowstart, E);

    // 4. atomic-free scatter of packed (val,col) into per-row segments
    bucket<<<(E + 511) / 512, 256, 0, stream>>>(erow, ecol, eval, rank,
                                                rowstart, cvp, E);

    // 5. per-row gather-reduce fused with self+bias+ReLU finalize
    row_gather<<<Nn / 4, 256, 0, stream>>>(rowstart, cvp, xrb, outp);
}

// Round 8
// 208.445 us; speedup vs baseline: 7.3972x; 1.0027x over previous
//
#include <hip/hip_runtime.h>
#include <hip/hip_fp16.h>

// Problem constants (DirectedGraphLayer): B=2, N=50000, FIN=128, FOUT=64, E=800000
#define Bc   2
#define Nn   50000
#define FINc 128
#define FOUTc 64
#define Mtot (Bc * Nn)          // 100000 combined (b,n) rows
#define CCOMB 128               // combined feature cols: [W cols 0..63 | W_self cols 0..63]
#define GB 1563                 // gemm blocks: ceil(100000/64)
#define CB 782                  // count blocks: ceil(800000/1024)

typedef __bf16 bf16x8 __attribute__((ext_vector_type(8)));
typedef float  f32x4  __attribute__((ext_vector_type(4)));

static __device__ inline unsigned short f2bf(float f) {
    unsigned int u = __float_as_uint(f);
    u += 0x7fffu + ((u >> 16) & 1u);       // round-to-nearest-even
    return (unsigned short)(u >> 16);
}

// ---------------------------------------------------------------------------
// pack_w: [W|W_self] -> fragment-major bf16 (32 KB), MFMA A-operand layout:
// entry (nt*4+kt)*64+lane holds Wc[k=kt*32+(lane>>4)*8+j][o=nt*16+(lane&15)].
// ---------------------------------------------------------------------------
__global__ __launch_bounds__(256) void pack_w(
    const float* __restrict__ W, const float* __restrict__ Ws,
    unsigned short* __restrict__ Bp)
{
    const int idx = blockIdx.x * 256 + threadIdx.x;
    const int lane = idx & 63;
    const int kt   = (idx >> 6) & 3;
    const int nt   = idx >> 8;
    const int n    = nt * 16 + (lane & 15);
    const int k0   = kt * 32 + (lane >> 4) * 8;
    unsigned short o8[8];
#pragma unroll
    for (int j = 0; j < 8; ++j) {
        const int f = k0 + j;
        const float v = (n < 64) ? W[f * FOUTc + n] : Ws[f * FOUTc + (n - 64)];
        o8[j] = f2bf(v);
    }
    *(uint4*)&Bp[(size_t)idx * 8] = *(uint4*)o8;
}

// ---------------------------------------------------------------------------
// gemm_count: blocks [0,CB) = padded-atomic row count + per-edge rank
// (FIRST so their atomic latency overlaps the gemm streaming, not a tail);
// blocks [CB,CB+GB) = bf16 MFMA GEMM (swapped operands: D = W^T x^T) with
// the 32 KB weight-fragment table staged in LDS.
// ---------------------------------------------------------------------------
__global__ __launch_bounds__(256) void gemm_count(
    const float* __restrict__ x, const unsigned short* __restrict__ Bp,
    const float* __restrict__ bself,
    unsigned short* __restrict__ xrb, float* __restrict__ outp,
    const int* __restrict__ erow, int* __restrict__ cntp,
    int* __restrict__ rank, int E)
{
    __shared__ unsigned short BpL[2048 * 8];   // 32 KB

    if (blockIdx.x < CB) {
        const int base = blockIdx.x * 1024 + threadIdx.x * 4;
        if (base + 4 <= E) {
            const int4 r4 = *(const int4*)&erow[base];
            const int k0 = atomicAdd(&cntp[(size_t)r4.x * 16], 1);
            const int k1 = atomicAdd(&cntp[(size_t)r4.y * 16], 1);
            const int k2 = atomicAdd(&cntp[(size_t)r4.z * 16], 1);
            const int k3 = atomicAdd(&cntp[(size_t)r4.w * 16], 1);
            *(int4*)&rank[base] = make_int4(k0, k1, k2, k3);
        }
        return;
    }

    // ---- GEMM half ----
    // stage weight fragments: 32 KB = 8 x uint4 per thread, striped
#pragma unroll
    for (int i = 0; i < 8; ++i)
        ((uint4*)BpL)[i * 256 + threadIdx.x] = ((const uint4*)Bp)[i * 256 + threadIdx.x];
    __syncthreads();

    const int lane = threadIdx.x & 63;
    const int quad = lane >> 4;
    const int mbase = (blockIdx.x - CB) * 64 + (threadIdx.x >> 6) * 16;

    const int mrow   = mbase + (lane & 15);
    const int mclamp = (mrow < Mtot) ? mrow : (Mtot - 1);
    const float* __restrict__ xrow = &x[(size_t)mclamp * FINc];

    f32x4 acc[8] = {};

#pragma unroll
    for (int kt = 0; kt < 4; ++kt) {
        const int k0 = kt * 32 + quad * 8;
        const float4 xa = *(const float4*)&xrow[k0];
        const float4 xb = *(const float4*)&xrow[k0 + 4];
        bf16x8 bf;                       // B operand: B[k][m], m=lane&15
        bf[0] = (__bf16)xa.x; bf[1] = (__bf16)xa.y;
        bf[2] = (__bf16)xa.z; bf[3] = (__bf16)xa.w;
        bf[4] = (__bf16)xb.x; bf[5] = (__bf16)xb.y;
        bf[6] = (__bf16)xb.z; bf[7] = (__bf16)xb.w;

#pragma unroll
        for (int nt = 0; nt < 8; ++nt) {
            const bf16x8 af = *(const bf16x8*)&BpL[(size_t)((nt * 4 + kt) * 64 + lane) * 8];
            // swapped: A = weights (m-index = feature o), B = x (n-index = row m)
            acc[nt] = __builtin_amdgcn_mfma_f32_16x16x32_bf16(af, bf, acc[nt], 0, 0, 0);
        }
    }

    // epilogue: lane owns row m; per nt, 4 consecutive features o = nt*16+quad*4+r
    const int m = mbase + (lane & 15);
    if (m < Mtot) {
        const int b = (m >= Nn) ? 1 : 0;
        const int n = m - b * Nn;
        unsigned short* __restrict__ xp = &xrb[(size_t)n * CCOMB + b * FOUTc];
        const int cq = quad * 4;
#pragma unroll
        for (int nt = 0; nt < 4; ++nt) {
            const int c = nt * 16 + cq;
            unsigned short h[4];
            h[0] = f2bf(acc[nt][0]); h[1] = f2bf(acc[nt][1]);
            h[2] = f2bf(acc[nt][2]); h[3] = f2bf(acc[nt][3]);
            *(uint2*)&xp[c] = *(uint2*)h;           // 8 B store
        }
        float* __restrict__ op = &outp[(size_t)m * FOUTc];
#pragma unroll
        for (int nt = 4; nt < 8; ++nt) {
            const int o = (nt - 4) * 16 + cq;
            const float4 b4 = *(const float4*)&bself[o];
            float4 v;
            v.x = acc[nt][0] + b4.x; v.y = acc[nt][1] + b4.y;
            v.z = acc[nt][2] + b4.z; v.w = acc[nt][3] + b4.w;
            *(float4*)&op[o] = v;                   // 16 B store, line-dense
        }
    }
}

// ---------------------------------------------------------------------------
// Hierarchical exclusive scan of padded counts -> rowstart.
// ---------------------------------------------------------------------------
__global__ __launch_bounds__(256) void block_sum(
    const int* __restrict__ cntp, int* __restrict__ bsum)
{
    __shared__ int s[256];
    const int t = threadIdx.x;
    const int idx = blockIdx.x * 256 + t;
    s[t] = (idx < Nn) ? cntp[(size_t)idx * 16] : 0;
    __syncthreads();
    for (int off = 128; off > 0; off >>= 1) {
        if (t < off) s[t] += s[t + off];
        __syncthreads();
    }
    if (t == 0) bsum[blockIdx.x] = s[0];
}

__global__ __launch_bounds__(256) void scan_bsum(
    const int* __restrict__ bsum, int* __restrict__ bscan, int nb)
{
    __shared__ int s[256];
    const int t = threadIdx.x;
    const int v = (t < nb) ? bsum[t] : 0;
    s[t] = v;
    __syncthreads();
    for (int off = 1; off < 256; off <<= 1) {
        const int add = (t >= off) ? s[t - off] : 0;
        __syncthreads();
        s[t] += add;
        __syncthreads();
    }
    if (t < nb) bscan[t] = s[t] - v;   // exclusive
}

__global__ __launch_bounds__(256) void fill_starts(
    const int* __restrict__ cntp, const int* __restrict__ bscan,
    int* __restrict__ rowstart, int E)
{
    __shared__ int s[256];
    const int t = threadIdx.x;
    const int idx = blockIdx.x * 256 + t;
    const int v = (idx < Nn) ? cntp[(size_t)idx * 16] : 0;
    s[t] = v;
    __syncthreads();
    for (int off = 1; off < 256; off <<= 1) {
        const int add = (t >= off) ? s[t - off] : 0;
        __syncthreads();
        s[t] += add;
        __syncthreads();
    }
    if (idx < Nn) rowstart[idx] = bscan[blockIdx.x] + (s[t] - v);
    if (idx == 0) rowstart[Nn] = E;
}

// ---------------------------------------------------------------------------
// bucket: NO atomics. pos = rowstart[row] + rank[e]; store packed 4 B
// (fp16 val without sign bit, 15 bits) << 17 | col (17 bits).
// ---------------------------------------------------------------------------
__global__ __launch_bounds__(256) void bucket(
    const int* __restrict__ erow, const int* __restrict__ ecol,
    const float* __restrict__ evalv, const int* __restrict__ rank,
    const int* __restrict__ rowstart, unsigned int* __restrict__ cvp, int E)
{
    const int e = blockIdx.x * 512 + threadIdx.x * 2;
    if (e + 2 > E) return;
    const int2   r2 = *(const int2*)&erow[e];
    const int2   c2 = *(const int2*)&ecol[e];
    const float2 v2 = *(const float2*)&evalv[e];
    const int2   k2 = *(const int2*)&rank[e];
    const unsigned int h0 = __half_as_ushort(__float2half(v2.x));  // val>=0 -> 15 bits
    const unsigned int h1 = __half_as_ushort(__float2half(v2.y));
    cvp[rowstart[r2.x] + k2.x] = (h0 << 17) | (unsigned int)c2.x;
    cvp[rowstart[r2.y] + k2.y] = (h1 << 17) | (unsigned int)c2.y;
}

// ---------------------------------------------------------------------------
// row_gather: one wave per row. 16 lanes per edge (4 edge-slots/wave); each
// lane covers 8 cols via one 16 B load of 8 bf16. 4 accumulator sets -> up to
// 16 edges in flight. Fused finalize: out = relu(self_pre + agg).
// ---------------------------------------------------------------------------
#define GATH16(EIDX, ACC)                                                     \
    {                                                                         \
        const unsigned int w = cvp[EIDX];                                     \
        const float vv = __half2float(__ushort_as_half(                       \
                             (unsigned short)(w >> 17)));                     \
        const uint4 raw = *(const uint4*)&xrb[(size_t)(w & 0x1FFFFu) * CCOMB + c0]; \
        ACC[0] = fmaf(vv, __uint_as_float(raw.x << 16),         ACC[0]);      \
        ACC[1] = fmaf(vv, __uint_as_float(raw.x & 0xffff0000u), ACC[1]);      \
        ACC[2] = fmaf(vv, __uint_as_float(raw.y << 16),         ACC[2]);      \
        ACC[3] = fmaf(vv, __uint_as_float(raw.y & 0xffff0000u), ACC[3]);      \
        ACC[4] = fmaf(vv, __uint_as_float(raw.z << 16),         ACC[4]);      \
        ACC[5] = fmaf(vv, __uint_as_float(raw.z & 0xffff0000u), ACC[5]);      \
        ACC[6] = fmaf(vv, __uint_as_float(raw.w << 16),         ACC[6]);      \
        ACC[7] = fmaf(vv, __uint_as_float(raw.w & 0xffff0000u), ACC[7]);      \
    }

__global__ __launch_bounds__(256) void row_gather(
    const int* __restrict__ rowstart, const unsigned int* __restrict__ cvp,
    const unsigned short* __restrict__ xrb, float* __restrict__ outp)
{
    const int lane = threadIdx.x & 63;
    int n = blockIdx.x * 4 + (threadIdx.x >> 6);
    n = __builtin_amdgcn_readfirstlane(n);   // wave-uniform -> scalar loads

    const int s    = rowstart[n];
    const int eend = rowstart[n + 1];
    const int sub  = lane >> 4;              // edge slot 0..3
    const int c0   = (lane & 15) * 8;        // 8 combined cols per lane

    float aA[8] = {0.f, 0.f, 0.f, 0.f, 0.f, 0.f, 0.f, 0.f};
    float aB[8] = {0.f, 0.f, 0.f, 0.f, 0.f, 0.f, 0.f, 0.f};
    float aC[8] = {0.f, 0.f, 0.f, 0.f, 0.f, 0.f, 0.f, 0.f};
    float aD[8] = {0.f, 0.f, 0.f, 0.f, 0.f, 0.f, 0.f, 0.f};

    int e = s;
    for (; e + 16 <= eend; e += 16) {
        GATH16(e + sub,      aA);
        GATH16(e + 4 + sub,  aB);
        GATH16(e + 8 + sub,  aC);
        GATH16(e + 12 + sub, aD);
    }
    if (e + 8 <= eend) {
        GATH16(e + sub,     aA);
        GATH16(e + 4 + sub, aB);
        e += 8;
    }
    for (; e < eend; e += 4) {
        if (e + sub < eend) GATH16(e + sub, aC);
    }

#pragma unroll
    for (int i = 0; i < 8; ++i) {
        aA[i] += aB[i];
        aC[i] += aD[i];
        aA[i] += aC[i];
        aA[i] += __shfl_down(aA[i], 16);
        aA[i] += __shfl_down(aA[i], 32);
    }

    if (lane < 16) {
        const int b = c0 >> 6;               // cols 0..63 -> b0, 64..127 -> b1
        const int o = c0 & 63;
        const size_t oidx = ((size_t)b * Nn + n) * FOUTc + o;
        float4 s0 = *(float4*)&outp[oidx];
        float4 s1 = *(float4*)&outp[oidx + 4];
        s0.x = fmaxf(s0.x + aA[0], 0.0f);
        s0.y = fmaxf(s0.y + aA[1], 0.0f);
        s0.z = fmaxf(s0.z + aA[2], 0.0f);
        s0.w = fmaxf(s0.w + aA[3], 0.0f);
        s1.x = fmaxf(s1.x + aA[4], 0.0f);
        s1.y = fmaxf(s1.y + aA[5], 0.0f);
        s1.z = fmaxf(s1.z + aA[6], 0.0f);
        s1.w = fmaxf(s1.w + aA[7], 0.0f);
        *(float4*)&outp[oidx]     = s0;
        *(float4*)&outp[oidx + 4] = s1;
    }
}

extern "C" void kernel_launch(void* const* d_in, const int* in_sizes, int n_in,
                              void* d_out, int out_size, void* d_ws, size_t ws_size,
                              hipStream_t stream)
{
    const float* x    = (const float*)d_in[0];
    const float* W    = (const float*)d_in[1];
    const float* Ws   = (const float*)d_in[2];
    const float* bs   = (const float*)d_in[3];
    const int*   erow = (const int*)d_in[4];
    const int*   ecol = (const int*)d_in[5];
    const float* eval = (const float*)d_in[6];
    float* outp = (float*)d_out;
    const int E = in_sizes[4];

    // workspace layout (every base 16 B aligned by construction)
    unsigned short* xrb = (unsigned short*)d_ws;         // N*128 bf16 = 12.8 MB
    unsigned int* cvp = (unsigned int*)(xrb + (size_t)Nn * CCOMB); // E u32 = 3.2 MB
    int* rank     = (int*)(cvp + E);                     // E ints = 3.2 MB
    int* rowstart = rank + E;                            // N+1 (+pad)
    int* cntp     = rowstart + (Nn + 4);                 // N*16 ints (line-padded) = 3.2 MB
    int* bsum     = cntp + (size_t)Nn * 16;              // 256
    int* bscan    = bsum + 256;                          // 256
    unsigned short* Bp = (unsigned short*)(bscan + 256); // 2048*8 bf16 = 32 KB

    const int NB = (Nn + 255) / 256;   // 196

    // 1. zero padded counters; pack weights
    hipMemsetAsync(cntp, 0, (size_t)Nn * 16 * sizeof(int), stream);
    pack_w<<<8, 256, 0, stream>>>(W, Ws, Bp);

    // 2. count blocks FIRST, then GEMM blocks (LDS-staged weight fragments)
    gemm_count<<<CB + GB, 256, 0, stream>>>(x, Bp, bs, xrb, outp,
                                            erow, cntp, rank, E);

    // 3. scan counts -> segment starts
    block_sum<<<NB, 256, 0, stream>>>(cntp, bsum);
    scan_bsum<<<1, 256, 0, stream>>>(bsum, bscan, NB);
    fill_starts<<<NB, 256, 0, stream>>>(cntp, bscan, rowstart, E);

    // 4. atomic-free scatter of packed (val,col) into per-row segments
    bucket<<<(E + 511) / 512, 256, 0, stream>>>(erow, ecol, eval, rank,
                                                rowstart, cvp, E);

    // 5. per-row gather-reduce fused with self+bias+ReLU finalize
    row_gather<<<Nn / 4, 256, 0, stream>>>(rowstart, cvp, xrb, outp);
}